// Round 5
// baseline (433.433 us; speedup 1.0000x reference)
//
#include <hip/hip_runtime.h>

#define LN_EPS 1e-5f

typedef float f32x4 __attribute__((ext_vector_type(4)));
typedef short bf16x8 __attribute__((ext_vector_type(8)));
typedef unsigned short u16x4 __attribute__((ext_vector_type(4)));

__device__ __forceinline__ unsigned short f2bf(float f) {
  unsigned int u = __float_as_uint(f);
  u = (u + 0x7fffu + ((u >> 16) & 1u)) >> 16;
  return (unsigned short)u;
}
__device__ __forceinline__ float bf2f(unsigned short h) {
  return __uint_as_float((unsigned int)h << 16);
}
__device__ __forceinline__ float sigm(float x) {
  return 1.f / (1.f + __expf(-x));
}

// ---------------- f32 -> bf16 convert (weights) ----------------
__global__ __launch_bounds__(256) void cvt_bf16(const float* __restrict__ in,
                                                unsigned short* __restrict__ out, int n) {
  int i = blockIdx.x * 256 + threadIdx.x;
  if (i < n) out[i] = f2bf(in[i]);
}

// ---------------- fused histogram over both destination arrays ----------------
__global__ __launch_bounds__(256) void hist2_kernel(const int* __restrict__ ci,
                                                    const int* __restrict__ vi,
                                                    int* __restrict__ cntC,
                                                    int* __restrict__ cntV, int E) {
  int e = blockIdx.x * 256 + threadIdx.x;
  if (e < E) {
    atomicAdd(&cntC[ci[e]], 1);
    atomicAdd(&cntV[vi[e]], 1);
  }
}

__global__ __launch_bounds__(256) void scan1(const int* __restrict__ cnt,
                                             int* __restrict__ off,
                                             int* __restrict__ bsum, int M) {
  __shared__ int s[256];
  int base = blockIdx.x * 1024 + threadIdx.x * 4;
  int v[4];
  int tot = 0;
#pragma unroll
  for (int i = 0; i < 4; ++i) {
    int idx = base + i;
    v[i] = (idx < M) ? cnt[idx] : 0;
    tot += v[i];
  }
  s[threadIdx.x] = tot;
  __syncthreads();
  for (int d = 1; d < 256; d <<= 1) {
    int t = (threadIdx.x >= d) ? s[threadIdx.x - d] : 0;
    __syncthreads();
    s[threadIdx.x] += t;
    __syncthreads();
  }
  int excl = s[threadIdx.x] - tot;
#pragma unroll
  for (int i = 0; i < 4; ++i) {
    int idx = base + i;
    if (idx < M) off[idx] = excl;
    excl += v[i];
  }
  if (threadIdx.x == 255) bsum[blockIdx.x] = s[255];
}

__global__ __launch_bounds__(256) void scan2(int* __restrict__ bsum, int nb) {
  __shared__ int s[256];
  __shared__ int carry;
  if (threadIdx.x == 0) carry = 0;
  __syncthreads();
  for (int base = 0; base < nb; base += 256) {
    int idx = base + threadIdx.x;
    int v = (idx < nb) ? bsum[idx] : 0;
    s[threadIdx.x] = v;
    __syncthreads();
    for (int d = 1; d < 256; d <<= 1) {
      int t = (threadIdx.x >= d) ? s[threadIdx.x - d] : 0;
      __syncthreads();
      s[threadIdx.x] += t;
      __syncthreads();
    }
    if (idx < nb) bsum[idx] = s[threadIdx.x] - v + carry;
    __syncthreads();
    if (threadIdx.x == 0) carry += s[255];
    __syncthreads();
  }
}

__global__ __launch_bounds__(256) void scan3(int* __restrict__ off,
                                             const int* __restrict__ bsum, int M, int E) {
  int idx = blockIdx.x * 256 + threadIdx.x;
  if (idx < M) off[idx] += bsum[idx >> 10];
  if (idx == M) off[M] = E;
}

// fused reorder: both directions in one pass over the edge list
__global__ __launch_bounds__(256) void reorder2_kernel(const int* __restrict__ ci,
                                                       const int* __restrict__ vi,
                                                       const float* __restrict__ ew,
                                                       int* __restrict__ curC,
                                                       int* __restrict__ curV,
                                                       int2* __restrict__ edataC,
                                                       int2* __restrict__ edataV, int E) {
  int e = blockIdx.x * 256 + threadIdx.x;
  if (e < E) {
    int c = ci[e], v = vi[e];
    int wb = __float_as_int(ew[e]);
    int pc = atomicAdd(&curC[c], 1);
    edataC[pc] = make_int2(v, wb);
    int pv = atomicAdd(&curV[v], 1);
    edataV[pv] = make_int2(c, wb);
  }
}

// ---------------- segmented gather*gate reduce -> mean (bf16 src/out) ----------------
// 256-thread block = 4 waves; wave w handles segment blockIdx.x*4+w; lane j: cols 2j,2j+1
__global__ __launch_bounds__(256) void seg_reduce(const int* __restrict__ off,
                                                  const int2* __restrict__ edata,
                                                  const float* __restrict__ gw,
                                                  const float* __restrict__ gb,
                                                  const unsigned short* __restrict__ src,
                                                  unsigned short* __restrict__ out, int M) {
  int seg = blockIdx.x * 4 + (threadIdx.x >> 6);
  if (seg >= M) return;
  int j = threadIdx.x & 63;
  int start = off[seg], end = off[seg + 1];
  float gwa = gw[2 * j], gwb = gw[2 * j + 1];
  float gba = gb[2 * j], gbb = gb[2 * j + 1];
  float a0 = 0.f, a1 = 0.f;
  int p = start;
  for (; p + 4 <= end; p += 4) {
    int2 e0 = edata[p], e1 = edata[p + 1], e2 = edata[p + 2], e3 = edata[p + 3];
    unsigned int v0 = *reinterpret_cast<const unsigned int*>(&src[(size_t)e0.x * 128 + 2 * j]);
    unsigned int v1 = *reinterpret_cast<const unsigned int*>(&src[(size_t)e1.x * 128 + 2 * j]);
    unsigned int v2 = *reinterpret_cast<const unsigned int*>(&src[(size_t)e2.x * 128 + 2 * j]);
    unsigned int v3 = *reinterpret_cast<const unsigned int*>(&src[(size_t)e3.x * 128 + 2 * j]);
    float w0 = __int_as_float(e0.y), w1 = __int_as_float(e1.y);
    float w2 = __int_as_float(e2.y), w3 = __int_as_float(e3.y);
    a0 += bf2f((unsigned short)(v0 & 0xffff)) * sigm(w0 * gwa + gba)
        + bf2f((unsigned short)(v1 & 0xffff)) * sigm(w1 * gwa + gba)
        + bf2f((unsigned short)(v2 & 0xffff)) * sigm(w2 * gwa + gba)
        + bf2f((unsigned short)(v3 & 0xffff)) * sigm(w3 * gwa + gba);
    a1 += bf2f((unsigned short)(v0 >> 16)) * sigm(w0 * gwb + gbb)
        + bf2f((unsigned short)(v1 >> 16)) * sigm(w1 * gwb + gbb)
        + bf2f((unsigned short)(v2 >> 16)) * sigm(w2 * gwb + gbb)
        + bf2f((unsigned short)(v3 >> 16)) * sigm(w3 * gwb + gbb);
  }
  if (p + 2 <= end) {
    int2 e0 = edata[p], e1 = edata[p + 1];
    unsigned int v0 = *reinterpret_cast<const unsigned int*>(&src[(size_t)e0.x * 128 + 2 * j]);
    unsigned int v1 = *reinterpret_cast<const unsigned int*>(&src[(size_t)e1.x * 128 + 2 * j]);
    float w0 = __int_as_float(e0.y), w1 = __int_as_float(e1.y);
    a0 += bf2f((unsigned short)(v0 & 0xffff)) * sigm(w0 * gwa + gba)
        + bf2f((unsigned short)(v1 & 0xffff)) * sigm(w1 * gwa + gba);
    a1 += bf2f((unsigned short)(v0 >> 16)) * sigm(w0 * gwb + gbb)
        + bf2f((unsigned short)(v1 >> 16)) * sigm(w1 * gwb + gbb);
    p += 2;
  }
  if (p < end) {
    int2 e0 = edata[p];
    unsigned int v0 = *reinterpret_cast<const unsigned int*>(&src[(size_t)e0.x * 128 + 2 * j]);
    float w0 = __int_as_float(e0.y);
    a0 += bf2f((unsigned short)(v0 & 0xffff)) * sigm(w0 * gwa + gba);
    a1 += bf2f((unsigned short)(v0 >> 16)) * sigm(w0 * gwb + gbb);
  }
  int cnt = end - start;
  float inv = 1.f / (float)(cnt > 1 ? cnt : 1);
  unsigned int packed = (unsigned int)f2bf(a0 * inv) | ((unsigned int)f2bf(a1 * inv) << 16);
  *reinterpret_cast<unsigned int*>(&out[(size_t)seg * 128 + 2 * j]) = packed;
}

// ------- MFMA GEMM (128x128 tile): out(M x 128) bf16 = bf16(X f32) @ Wbf^T + bias -------
// 4 waves; wave wv owns cols [wv*32, wv*32+32), all 128 rows: 8 mf x 2 nf MFMA per K-step.
template <int K>
__global__ __launch_bounds__(256) void gemm_lin_mfma(const float* __restrict__ X,
                                                     const unsigned short* __restrict__ Wbf,
                                                     const float* __restrict__ bias,
                                                     unsigned short* __restrict__ out, int M) {
  constexpr int NK = K / 32;
  __shared__ unsigned short Xs[128][40];   // 80B row stride
  __shared__ unsigned short Bs[128][40];
  const int tid = threadIdx.x;
  const int lane = tid & 63, wv = tid >> 6;
  const int lr = lane & 15, lg = lane >> 4;
  const int row0 = blockIdx.x * 128;

  f32x4 acc[8][2];
#pragma unroll
  for (int mf = 0; mf < 8; ++mf)
#pragma unroll
    for (int nf = 0; nf < 2; ++nf) acc[mf][nf] = (f32x4)(0.f);

  float4 fr[4];
  bf16x8 wr[2];

  auto loadX = [&](int k0) {
#pragma unroll
    for (int it = 0; it < 4; ++it) {
      int q = tid + it * 256;
      int r = q >> 3, kq = (q & 7) * 4;
      int grow = row0 + r;
      fr[it] = (grow < M) ? *reinterpret_cast<const float4*>(&X[(size_t)grow * K + k0 + kq])
                          : make_float4(0.f, 0.f, 0.f, 0.f);
    }
  };
  auto loadW = [&](int k0) {
#pragma unroll
    for (int it = 0; it < 2; ++it) {
      int q = tid + it * 256;
      int n = q >> 2, kq = (q & 3) * 8;
      wr[it] = *reinterpret_cast<const bf16x8*>(&Wbf[(size_t)n * K + k0 + kq]);
    }
  };
  auto writeLDS = [&]() {
#pragma unroll
    for (int it = 0; it < 4; ++it) {
      int q = tid + it * 256;
      int r = q >> 3, kq = (q & 7) * 4;
      u16x4 p = {f2bf(fr[it].x), f2bf(fr[it].y), f2bf(fr[it].z), f2bf(fr[it].w)};
      *reinterpret_cast<u16x4*>(&Xs[r][kq]) = p;
    }
#pragma unroll
    for (int it = 0; it < 2; ++it) {
      int q = tid + it * 256;
      int n = q >> 2, kq = (q & 3) * 8;
      *reinterpret_cast<bf16x8*>(&Bs[n][kq]) = wr[it];
    }
  };

  loadX(0);
  loadW(0);
  writeLDS();
  __syncthreads();

  for (int ks = 0; ks < NK; ++ks) {
    if (ks + 1 < NK) {
      loadX((ks + 1) * 32);
      loadW((ks + 1) * 32);
    }
    bf16x8 b[2];
#pragma unroll
    for (int nf = 0; nf < 2; ++nf)
      b[nf] = *reinterpret_cast<const bf16x8*>(&Bs[wv * 32 + nf * 16 + lr][lg * 8]);
#pragma unroll
    for (int mf = 0; mf < 8; ++mf) {
      bf16x8 a = *reinterpret_cast<const bf16x8*>(&Xs[mf * 16 + lr][lg * 8]);
#pragma unroll
      for (int nf = 0; nf < 2; ++nf)
        acc[mf][nf] = __builtin_amdgcn_mfma_f32_16x16x32_bf16(a, b[nf], acc[mf][nf], 0, 0, 0);
    }
    __syncthreads();
    if (ks + 1 < NK) {
      writeLDS();
      __syncthreads();
    }
  }

  int col[2];
  float bv[2];
#pragma unroll
  for (int nf = 0; nf < 2; ++nf) {
    col[nf] = wv * 32 + nf * 16 + lr;
    bv[nf] = bias[col[nf]];
  }
#pragma unroll
  for (int mf = 0; mf < 8; ++mf)
#pragma unroll
    for (int reg = 0; reg < 4; ++reg) {
      int grow = row0 + mf * 16 + lg * 4 + reg;
      if (grow < M) {
#pragma unroll
        for (int nf = 0; nf < 2; ++nf)
          out[(size_t)grow * 128 + col[nf]] = f2bf(acc[mf][nf][reg] + bv[nf]);
      }
    }
}

// ------- MFMA update GEMM (128x128 tile): X = concat(agg bf16, base f32); LN; ReLU -------
__global__ __launch_bounds__(256) void gemm_upd_mfma(const unsigned short* __restrict__ agg,
                                                     const float* __restrict__ base,
                                                     const unsigned short* __restrict__ Wbf,
                                                     const float* __restrict__ bias,
                                                     const float* __restrict__ lng,
                                                     const float* __restrict__ lnb,
                                                     float* __restrict__ out, int M) {
  constexpr int K = 256, NK = 8;
  __shared__ unsigned short Xs[128][40];
  __shared__ unsigned short Bs[128][40];
  const int tid = threadIdx.x;
  const int lane = tid & 63, wv = tid >> 6;
  const int lr = lane & 15, lg = lane >> 4;
  const int row0 = blockIdx.x * 128;

  f32x4 acc[8][2];
#pragma unroll
  for (int mf = 0; mf < 8; ++mf)
#pragma unroll
    for (int nf = 0; nf < 2; ++nf) acc[mf][nf] = (f32x4)(0.f);

  u16x4 hr[4];
  float4 fr[4];
  bf16x8 wr[2];

  // k0 < 128: X from agg (bf16); k0 >= 128: X from base (f32) — uniform per K-step
  auto loadX = [&](int k0) {
    if (k0 < 128) {
#pragma unroll
      for (int it = 0; it < 4; ++it) {
        int q = tid + it * 256;
        int r = q >> 3, kq = (q & 7) * 4;
        int grow = row0 + r;
        hr[it] = (grow < M) ? *reinterpret_cast<const u16x4*>(&agg[(size_t)grow * 128 + k0 + kq])
                            : (u16x4){0, 0, 0, 0};
      }
    } else {
#pragma unroll
      for (int it = 0; it < 4; ++it) {
        int q = tid + it * 256;
        int r = q >> 3, kq = (q & 7) * 4;
        int grow = row0 + r;
        fr[it] = (grow < M)
                     ? *reinterpret_cast<const float4*>(&base[(size_t)grow * 128 + (k0 - 128) + kq])
                     : make_float4(0.f, 0.f, 0.f, 0.f);
      }
    }
  };
  auto loadW = [&](int k0) {
#pragma unroll
    for (int it = 0; it < 2; ++it) {
      int q = tid + it * 256;
      int n = q >> 2, kq = (q & 3) * 8;
      wr[it] = *reinterpret_cast<const bf16x8*>(&Wbf[(size_t)n * K + k0 + kq]);
    }
  };
  auto writeLDS = [&](int k0) {
#pragma unroll
    for (int it = 0; it < 4; ++it) {
      int q = tid + it * 256;
      int r = q >> 3, kq = (q & 7) * 4;
      if (k0 < 128) {
        *reinterpret_cast<u16x4*>(&Xs[r][kq]) = hr[it];
      } else {
        u16x4 p = {f2bf(fr[it].x), f2bf(fr[it].y), f2bf(fr[it].z), f2bf(fr[it].w)};
        *reinterpret_cast<u16x4*>(&Xs[r][kq]) = p;
      }
    }
#pragma unroll
    for (int it = 0; it < 2; ++it) {
      int q = tid + it * 256;
      int n = q >> 2, kq = (q & 3) * 8;
      *reinterpret_cast<bf16x8*>(&Bs[n][kq]) = wr[it];
    }
  };

  loadX(0);
  loadW(0);
  writeLDS(0);
  __syncthreads();

  for (int ks = 0; ks < NK; ++ks) {
    int k0n = (ks + 1) * 32;
    if (ks + 1 < NK) {
      loadX(k0n);
      loadW(k0n);
    }
    bf16x8 b[2];
#pragma unroll
    for (int nf = 0; nf < 2; ++nf)
      b[nf] = *reinterpret_cast<const bf16x8*>(&Bs[wv * 32 + nf * 16 + lr][lg * 8]);
#pragma unroll
    for (int mf = 0; mf < 8; ++mf) {
      bf16x8 a = *reinterpret_cast<const bf16x8*>(&Xs[mf * 16 + lr][lg * 8]);
#pragma unroll
      for (int nf = 0; nf < 2; ++nf)
        acc[mf][nf] = __builtin_amdgcn_mfma_f32_16x16x32_bf16(a, b[nf], acc[mf][nf], 0, 0, 0);
    }
    __syncthreads();
    if (ks + 1 < NK) {
      writeLDS(k0n);
      __syncthreads();
    }
  }

  // epilogue: bias in-place, LN across 4 waves (partials via LDS aliased over Xs), ReLU
  float* sredS = (float*)&Xs[0][0];   // 128*4 floats
  float* sredQ = sredS + 512;         // 128*4 floats

  int col[2];
  float bv[2], gv[2], lv[2];
#pragma unroll
  for (int nf = 0; nf < 2; ++nf) {
    col[nf] = wv * 32 + nf * 16 + lr;
    bv[nf] = bias[col[nf]];
    gv[nf] = lng[col[nf]];
    lv[nf] = lnb[col[nf]];
  }

#pragma unroll
  for (int mf = 0; mf < 8; ++mf)
#pragma unroll
    for (int reg = 0; reg < 4; ++reg) {
      float z0 = acc[mf][0][reg] + bv[0];
      float z1 = acc[mf][1][reg] + bv[1];
      acc[mf][0][reg] = z0;
      acc[mf][1][reg] = z1;
      float s = z0 + z1;
      float q = z0 * z0 + z1 * z1;
#pragma unroll
      for (int m = 1; m < 16; m <<= 1) {
        s += __shfl_xor(s, m);
        q += __shfl_xor(q, m);
      }
      if (lr == 0) {
        int tr = mf * 16 + lg * 4 + reg;
        sredS[tr * 4 + wv] = s;
        sredQ[tr * 4 + wv] = q;
      }
    }
  __syncthreads();
#pragma unroll
  for (int mf = 0; mf < 8; ++mf)
#pragma unroll
    for (int reg = 0; reg < 4; ++reg) {
      int tr = mf * 16 + lg * 4 + reg;
      f32x4 S4 = *reinterpret_cast<const f32x4*>(&sredS[tr * 4]);
      f32x4 Q4 = *reinterpret_cast<const f32x4*>(&sredQ[tr * 4]);
      float S = S4[0] + S4[1] + S4[2] + S4[3];
      float Q = Q4[0] + Q4[1] + Q4[2] + Q4[3];
      float mean = S * (1.f / 128.f);
      float var = Q * (1.f / 128.f) - mean * mean;
      float rstd = rsqrtf(var + LN_EPS);
      int grow = row0 + tr;
      if (grow < M) {
#pragma unroll
        for (int nf = 0; nf < 2; ++nf) {
          float y = (acc[mf][nf][reg] - mean) * rstd * gv[nf] + lv[nf];
          out[(size_t)grow * 128 + col[nf]] = fmaxf(y, 0.f);
        }
      }
    }
}

extern "C" void kernel_launch(void* const* d_in, const int* in_sizes, int n_in,
                              void* d_out, int out_size, void* d_ws, size_t ws_size,
                              hipStream_t stream) {
  const float* vh = (const float*)d_in[0];
  const float* ch = (const float*)d_in[1];
  const int* ei = (const int*)d_in[2];   // [ci(E), vi(E)]
  const float* ew = (const float*)d_in[3];
  const float* v2c_lin_w = (const float*)d_in[4];
  const float* v2c_lin_b = (const float*)d_in[5];
  const float* v2c_gate_w = (const float*)d_in[6];
  const float* v2c_gate_b = (const float*)d_in[7];
  const float* v2c_upd_w = (const float*)d_in[8];
  const float* v2c_upd_b = (const float*)d_in[9];
  const float* v2c_ln_g = (const float*)d_in[10];
  const float* v2c_ln_b = (const float*)d_in[11];
  const float* c2v_lin_w = (const float*)d_in[12];
  const float* c2v_lin_b = (const float*)d_in[13];
  const float* c2v_gate_w = (const float*)d_in[14];
  const float* c2v_gate_b = (const float*)d_in[15];
  const float* c2v_upd_w = (const float*)d_in[16];
  const float* c2v_upd_b = (const float*)d_in[17];
  const float* c2v_ln_g = (const float*)d_in[18];
  const float* c2v_ln_b = (const float*)d_in[19];

  const int N = in_sizes[0] / 128;
  const int C = in_sizes[1] / 128;
  const int E = in_sizes[3];
  const int* ci = ei;
  const int* vi = ei + E;

  unsigned short* tmpNV = (unsigned short*)d_ws;        // N*128 bf16: tmp_v, later agg_v
  unsigned short* aggC = tmpNV + (size_t)N * 128;       // C*128 bf16: agg_c, later tmp_c
  unsigned short* wbfLinV = aggC + (size_t)C * 128;     // 128*128
  unsigned short* wbfUpdV = wbfLinV + 128 * 128;        // 128*256
  unsigned short* wbfLinC = wbfUpdV + 128 * 256;        // 128*128
  unsigned short* wbfUpdC = wbfLinC + 128 * 128;        // 128*256
  int* offC = (int*)(wbfUpdC + 128 * 256);              // C+1
  int* offV = offC + (C + 1);                           // N+1
  // 8-byte align for int2
  size_t ofs = (size_t)(offV + (N + 1) - (int*)d_ws);
  ofs = (ofs + 1) & ~(size_t)1;
  int2* edataC = (int2*)((int*)d_ws + ofs);             // E
  int2* edataV = edataC + E;                            // E
  // sort scratch aliased into aggC region (dead until seg_reduce writes it)
  int* cntC = (int*)aggC;                               // C
  int* cntV = cntC + C;                                 // N
  int* curC = cntV + N;                                 // C
  int* curV = curC + C;                                 // N
  int* bsumS = curV + N;                                // ~256

  float* vhNew = (float*)d_out;
  float* chNew = (float*)d_out + (size_t)N * 128;

  // weight f32->bf16
  cvt_bf16<<<(128 * 128 + 255) / 256, 256, 0, stream>>>(v2c_lin_w, wbfLinV, 128 * 128);
  cvt_bf16<<<(128 * 256 + 255) / 256, 256, 0, stream>>>(v2c_upd_w, wbfUpdV, 128 * 256);
  cvt_bf16<<<(128 * 128 + 255) / 256, 256, 0, stream>>>(c2v_lin_w, wbfLinC, 128 * 128);
  cvt_bf16<<<(128 * 256 + 255) / 256, 256, 0, stream>>>(c2v_upd_w, wbfUpdC, 128 * 256);

  const int egrid = (E + 255) / 256;

  // ---- counting sorts (fused hist + fused reorder) ----
  hipMemsetAsync(cntC, 0, (size_t)(C + N) * sizeof(int), stream);
  hist2_kernel<<<egrid, 256, 0, stream>>>(ci, vi, cntC, cntV, E);
  {
    int nb = (C + 1023) / 1024;
    scan1<<<nb, 256, 0, stream>>>(cntC, offC, bsumS, C);
    scan2<<<1, 256, 0, stream>>>(bsumS, nb);
    scan3<<<(C + 1 + 255) / 256, 256, 0, stream>>>(offC, bsumS, C, E);
  }
  {
    int nb = (N + 1023) / 1024;
    scan1<<<nb, 256, 0, stream>>>(cntV, offV, bsumS, N);
    scan2<<<1, 256, 0, stream>>>(bsumS, nb);
    scan3<<<(N + 1 + 255) / 256, 256, 0, stream>>>(offV, bsumS, N, E);
  }
  hipMemcpyAsync(curC, offC, (size_t)C * sizeof(int), hipMemcpyDeviceToDevice, stream);
  hipMemcpyAsync(curV, offV, (size_t)N * sizeof(int), hipMemcpyDeviceToDevice, stream);
  reorder2_kernel<<<egrid, 256, 0, stream>>>(ci, vi, ew, curC, curV, edataC, edataV, E);

  // ---- v2c ----
  gemm_lin_mfma<128><<<(N + 127) / 128, 256, 0, stream>>>(vh, wbfLinV, v2c_lin_b, tmpNV, N);
  seg_reduce<<<(C + 3) / 4, 256, 0, stream>>>(offC, edataC, v2c_gate_w, v2c_gate_b,
                                              tmpNV, aggC, C);
  gemm_upd_mfma<<<(C + 127) / 128, 256, 0, stream>>>(aggC, ch, wbfUpdV, v2c_upd_b,
                                                     v2c_ln_g, v2c_ln_b, chNew, C);

  // ---- c2v ----
  unsigned short* tmpC = aggC;   // reuse (agg_c dead after gemm_upd)
  gemm_lin_mfma<128><<<(C + 127) / 128, 256, 0, stream>>>(chNew, wbfLinC, c2v_lin_b, tmpC, C);
  unsigned short* aggV = tmpNV;  // reuse (tmp_v dead after v2c seg_reduce)
  seg_reduce<<<(N + 3) / 4, 256, 0, stream>>>(offV, edataV, c2v_gate_w, c2v_gate_b,
                                              tmpC, aggV, N);
  gemm_upd_mfma<<<(N + 127) / 128, 256, 0, stream>>>(aggV, vh, wbfUpdC, c2v_upd_b,
                                                     c2v_ln_g, c2v_ln_b, vhNew, N);
}

// Round 6
// 419.333 us; speedup vs baseline: 1.0336x; 1.0336x over previous
//
#include <hip/hip_runtime.h>

#define LN_EPS 1e-5f

typedef float f32x4 __attribute__((ext_vector_type(4)));
typedef short bf16x8 __attribute__((ext_vector_type(8)));
typedef unsigned short u16x4 __attribute__((ext_vector_type(4)));

__device__ __forceinline__ unsigned short f2bf(float f) {
  unsigned int u = __float_as_uint(f);
  u = (u + 0x7fffu + ((u >> 16) & 1u)) >> 16;
  return (unsigned short)u;
}
__device__ __forceinline__ float bf2f(unsigned short h) {
  return __uint_as_float((unsigned int)h << 16);
}
__device__ __forceinline__ float sigm(float x) {
  return 1.f / (1.f + __expf(-x));
}

// ---------------- fused f32 -> bf16 convert for all 4 weight mats ----------------
__global__ __launch_bounds__(256) void cvt4_bf16(const float* __restrict__ a,
                                                 const float* __restrict__ b,
                                                 const float* __restrict__ c,
                                                 const float* __restrict__ d,
                                                 unsigned short* __restrict__ oa,
                                                 unsigned short* __restrict__ ob,
                                                 unsigned short* __restrict__ oc,
                                                 unsigned short* __restrict__ od) {
  int i = blockIdx.x * 256 + threadIdx.x;
  if (i < 16384) oa[i] = f2bf(a[i]);
  else if (i < 49152) ob[i - 16384] = f2bf(b[i - 16384]);
  else if (i < 65536) oc[i - 49152] = f2bf(c[i - 49152]);
  else if (i < 98304) od[i - 65536] = f2bf(d[i - 65536]);
}

// ---------------- fused histogram over both destination arrays ----------------
__global__ __launch_bounds__(256) void hist2_kernel(const int* __restrict__ ci,
                                                    const int* __restrict__ vi,
                                                    int* __restrict__ cntC,
                                                    int* __restrict__ cntV, int E) {
  int e = blockIdx.x * 256 + threadIdx.x;
  if (e < E) {
    atomicAdd(&cntC[ci[e]], 1);
    atomicAdd(&cntV[vi[e]], 1);
  }
}

__global__ __launch_bounds__(256) void scan1(const int* __restrict__ cnt,
                                             int* __restrict__ off,
                                             int* __restrict__ bsum, int M) {
  __shared__ int s[256];
  int base = blockIdx.x * 1024 + threadIdx.x * 4;
  int v[4];
  int tot = 0;
#pragma unroll
  for (int i = 0; i < 4; ++i) {
    int idx = base + i;
    v[i] = (idx < M) ? cnt[idx] : 0;
    tot += v[i];
  }
  s[threadIdx.x] = tot;
  __syncthreads();
  for (int d = 1; d < 256; d <<= 1) {
    int t = (threadIdx.x >= d) ? s[threadIdx.x - d] : 0;
    __syncthreads();
    s[threadIdx.x] += t;
    __syncthreads();
  }
  int excl = s[threadIdx.x] - tot;
#pragma unroll
  for (int i = 0; i < 4; ++i) {
    int idx = base + i;
    if (idx < M) off[idx] = excl;
    excl += v[i];
  }
  if (threadIdx.x == 255) bsum[blockIdx.x] = s[255];
}

__global__ __launch_bounds__(256) void scan2(int* __restrict__ bsum, int nb) {
  __shared__ int s[256];
  __shared__ int carry;
  if (threadIdx.x == 0) carry = 0;
  __syncthreads();
  for (int base = 0; base < nb; base += 256) {
    int idx = base + threadIdx.x;
    int v = (idx < nb) ? bsum[idx] : 0;
    s[threadIdx.x] = v;
    __syncthreads();
    for (int d = 1; d < 256; d <<= 1) {
      int t = (threadIdx.x >= d) ? s[threadIdx.x - d] : 0;
      __syncthreads();
      s[threadIdx.x] += t;
      __syncthreads();
    }
    if (idx < nb) bsum[idx] = s[threadIdx.x] - v + carry;
    __syncthreads();
    if (threadIdx.x == 0) carry += s[255];
    __syncthreads();
  }
}

// scan3: finalize offsets AND init reorder cursors
__global__ __launch_bounds__(256) void scan3(int* __restrict__ off,
                                             int* __restrict__ cur,
                                             const int* __restrict__ bsum, int M, int E) {
  int idx = blockIdx.x * 256 + threadIdx.x;
  if (idx < M) {
    int v = off[idx] + bsum[idx >> 10];
    off[idx] = v;
    cur[idx] = v;
  }
  if (idx == M) off[M] = E;
}

// fused reorder: both directions in one pass over the edge list
__global__ __launch_bounds__(256) void reorder2_kernel(const int* __restrict__ ci,
                                                       const int* __restrict__ vi,
                                                       const float* __restrict__ ew,
                                                       int* __restrict__ curC,
                                                       int* __restrict__ curV,
                                                       int2* __restrict__ edataC,
                                                       int2* __restrict__ edataV, int E) {
  int e = blockIdx.x * 256 + threadIdx.x;
  if (e < E) {
    int c = ci[e], v = vi[e];
    int wb = __float_as_int(ew[e]);
    int pc = atomicAdd(&curC[c], 1);
    edataC[pc] = make_int2(v, wb);
    int pv = atomicAdd(&curV[v], 1);
    edataV[pv] = make_int2(c, wb);
  }
}

// ---------------- segmented gather*gate reduce -> mean (bf16 src/out) ----------------
// 256-thread block = 4 waves; wave w handles segment blockIdx.x*4+w; lane j: cols 2j,2j+1
__global__ __launch_bounds__(256) void seg_reduce(const int* __restrict__ off,
                                                  const int2* __restrict__ edata,
                                                  const float* __restrict__ gw,
                                                  const float* __restrict__ gb,
                                                  const unsigned short* __restrict__ src,
                                                  int srcStride,
                                                  unsigned short* __restrict__ out,
                                                  int outStride, int M) {
  int seg = blockIdx.x * 4 + (threadIdx.x >> 6);
  if (seg >= M) return;
  int j = threadIdx.x & 63;
  int start = off[seg], end = off[seg + 1];
  float gwa = gw[2 * j], gwb = gw[2 * j + 1];
  float gba = gb[2 * j], gbb = gb[2 * j + 1];
  float a0 = 0.f, a1 = 0.f;
  int p = start;
  for (; p + 4 <= end; p += 4) {
    int2 e0 = edata[p], e1 = edata[p + 1], e2 = edata[p + 2], e3 = edata[p + 3];
    unsigned int v0 = *reinterpret_cast<const unsigned int*>(&src[(size_t)e0.x * srcStride + 2 * j]);
    unsigned int v1 = *reinterpret_cast<const unsigned int*>(&src[(size_t)e1.x * srcStride + 2 * j]);
    unsigned int v2 = *reinterpret_cast<const unsigned int*>(&src[(size_t)e2.x * srcStride + 2 * j]);
    unsigned int v3 = *reinterpret_cast<const unsigned int*>(&src[(size_t)e3.x * srcStride + 2 * j]);
    float w0 = __int_as_float(e0.y), w1 = __int_as_float(e1.y);
    float w2 = __int_as_float(e2.y), w3 = __int_as_float(e3.y);
    a0 += bf2f((unsigned short)(v0 & 0xffff)) * sigm(w0 * gwa + gba)
        + bf2f((unsigned short)(v1 & 0xffff)) * sigm(w1 * gwa + gba)
        + bf2f((unsigned short)(v2 & 0xffff)) * sigm(w2 * gwa + gba)
        + bf2f((unsigned short)(v3 & 0xffff)) * sigm(w3 * gwa + gba);
    a1 += bf2f((unsigned short)(v0 >> 16)) * sigm(w0 * gwb + gbb)
        + bf2f((unsigned short)(v1 >> 16)) * sigm(w1 * gwb + gbb)
        + bf2f((unsigned short)(v2 >> 16)) * sigm(w2 * gwb + gbb)
        + bf2f((unsigned short)(v3 >> 16)) * sigm(w3 * gwb + gbb);
  }
  if (p + 2 <= end) {
    int2 e0 = edata[p], e1 = edata[p + 1];
    unsigned int v0 = *reinterpret_cast<const unsigned int*>(&src[(size_t)e0.x * srcStride + 2 * j]);
    unsigned int v1 = *reinterpret_cast<const unsigned int*>(&src[(size_t)e1.x * srcStride + 2 * j]);
    float w0 = __int_as_float(e0.y), w1 = __int_as_float(e1.y);
    a0 += bf2f((unsigned short)(v0 & 0xffff)) * sigm(w0 * gwa + gba)
        + bf2f((unsigned short)(v1 & 0xffff)) * sigm(w1 * gwa + gba);
    a1 += bf2f((unsigned short)(v0 >> 16)) * sigm(w0 * gwb + gbb)
        + bf2f((unsigned short)(v1 >> 16)) * sigm(w1 * gwb + gbb);
    p += 2;
  }
  if (p < end) {
    int2 e0 = edata[p];
    unsigned int v0 = *reinterpret_cast<const unsigned int*>(&src[(size_t)e0.x * srcStride + 2 * j]);
    float w0 = __int_as_float(e0.y);
    a0 += bf2f((unsigned short)(v0 & 0xffff)) * sigm(w0 * gwa + gba);
    a1 += bf2f((unsigned short)(v0 >> 16)) * sigm(w0 * gwb + gbb);
  }
  int cnt = end - start;
  float inv = 1.f / (float)(cnt > 1 ? cnt : 1);
  unsigned int packed = (unsigned int)f2bf(a0 * inv) | ((unsigned int)f2bf(a1 * inv) << 16);
  *reinterpret_cast<unsigned int*>(&out[(size_t)seg * outStride + 2 * j]) = packed;
}

// ------- MFMA GEMM (64x128 tile, round-4 structure): out bf16 = bf16(X f32) @ Wbf^T + bias
// OS: output row stride. WBF: also store the staged bf16(X) tile to bfdst[:,128:256] (Xcat).
template <int K, int OS, bool WBF>
__global__ __launch_bounds__(256) void gemm_lin_mfma(const float* __restrict__ X,
                                                     const unsigned short* __restrict__ Wbf,
                                                     const float* __restrict__ bias,
                                                     unsigned short* __restrict__ out,
                                                     unsigned short* __restrict__ bfdst,
                                                     int M) {
  __shared__ unsigned short Xs[64][40];   // 80B row stride: conflict-free b128 reads
  __shared__ unsigned short Bs[128][40];
  const int tid = threadIdx.x;
  const int lane = tid & 63, wv = tid >> 6;
  const int lr = lane & 15, lg = lane >> 4;
  const int row0 = blockIdx.x * 64;

  f32x4 acc[4][2];
#pragma unroll
  for (int mf = 0; mf < 4; ++mf)
#pragma unroll
    for (int nf = 0; nf < 2; ++nf) acc[mf][nf] = (f32x4)(0.f);

  for (int k0 = 0; k0 < K; k0 += 32) {
#pragma unroll
    for (int it = 0; it < 2; ++it) {
      int q = tid + it * 256;
      int r = q >> 3, kq = (q & 7) * 4;
      int grow = row0 + r;
      float4 v = make_float4(0.f, 0.f, 0.f, 0.f);
      if (grow < M) v = *reinterpret_cast<const float4*>(&X[(size_t)grow * K + k0 + kq]);
      u16x4 p = {f2bf(v.x), f2bf(v.y), f2bf(v.z), f2bf(v.w)};
      *reinterpret_cast<u16x4*>(&Xs[r][kq]) = p;
      if (WBF && grow < M)
        *reinterpret_cast<u16x4*>(&bfdst[(size_t)grow * 256 + 128 + k0 + kq]) = p;
    }
#pragma unroll
    for (int it = 0; it < 2; ++it) {
      int q = tid + it * 256;
      int n = q >> 2, kq = (q & 3) * 8;
      bf16x8 wrow = *reinterpret_cast<const bf16x8*>(&Wbf[(size_t)n * K + k0 + kq]);
      *reinterpret_cast<bf16x8*>(&Bs[n][kq]) = wrow;
    }
    __syncthreads();
    bf16x8 a[4], b[2];
#pragma unroll
    for (int mf = 0; mf < 4; ++mf)
      a[mf] = *reinterpret_cast<const bf16x8*>(&Xs[mf * 16 + lr][lg * 8]);
#pragma unroll
    for (int nf = 0; nf < 2; ++nf)
      b[nf] = *reinterpret_cast<const bf16x8*>(&Bs[wv * 32 + nf * 16 + lr][lg * 8]);
#pragma unroll
    for (int mf = 0; mf < 4; ++mf)
#pragma unroll
      for (int nf = 0; nf < 2; ++nf)
        acc[mf][nf] = __builtin_amdgcn_mfma_f32_16x16x32_bf16(a[mf], b[nf], acc[mf][nf], 0, 0, 0);
    __syncthreads();
  }

  int col[2];
  float bv[2];
#pragma unroll
  for (int nf = 0; nf < 2; ++nf) {
    col[nf] = wv * 32 + nf * 16 + lr;
    bv[nf] = bias[col[nf]];
  }
#pragma unroll
  for (int mf = 0; mf < 4; ++mf)
#pragma unroll
    for (int reg = 0; reg < 4; ++reg) {
      int grow = row0 + mf * 16 + lg * 4 + reg;
      if (grow < M) {
#pragma unroll
        for (int nf = 0; nf < 2; ++nf)
          out[(size_t)grow * OS + col[nf]] = f2bf(acc[mf][nf][reg] + bv[nf]);
      }
    }
}

// ------- MFMA update GEMM (64x128, round-4): X = concat(agg bf16, base f32); LN; ReLU ----
__global__ __launch_bounds__(256) void gemm_upd_mix(const unsigned short* __restrict__ agg,
                                                    const float* __restrict__ base,
                                                    const unsigned short* __restrict__ Wbf,
                                                    const float* __restrict__ bias,
                                                    const float* __restrict__ lng,
                                                    const float* __restrict__ lnb,
                                                    float* __restrict__ out, int M) {
  constexpr int K = 256;
  __shared__ unsigned short Xs[64][40];
  __shared__ unsigned short Bs[128][40];
  __shared__ float sredS[64][4];
  __shared__ float sredQ[64][4];
  const int tid = threadIdx.x;
  const int lane = tid & 63, wv = tid >> 6;
  const int lr = lane & 15, lg = lane >> 4;
  const int row0 = blockIdx.x * 64;

  f32x4 acc[4][2];
#pragma unroll
  for (int mf = 0; mf < 4; ++mf)
#pragma unroll
    for (int nf = 0; nf < 2; ++nf) acc[mf][nf] = (f32x4)(0.f);

  for (int k0 = 0; k0 < K; k0 += 32) {
#pragma unroll
    for (int it = 0; it < 2; ++it) {
      int q = tid + it * 256;
      int r = q >> 3, kq = (q & 7) * 4;
      int grow = row0 + r, gk = k0 + kq;
      u16x4 p = {0, 0, 0, 0};
      if (grow < M) {
        if (gk < 128) {
          p = *reinterpret_cast<const u16x4*>(&agg[(size_t)grow * 128 + gk]);
        } else {
          float4 v = *reinterpret_cast<const float4*>(&base[(size_t)grow * 128 + (gk - 128)]);
          p = {f2bf(v.x), f2bf(v.y), f2bf(v.z), f2bf(v.w)};
        }
      }
      *reinterpret_cast<u16x4*>(&Xs[r][kq]) = p;
    }
#pragma unroll
    for (int it = 0; it < 2; ++it) {
      int q = tid + it * 256;
      int n = q >> 2, kq = (q & 3) * 8;
      bf16x8 wrow = *reinterpret_cast<const bf16x8*>(&Wbf[(size_t)n * K + k0 + kq]);
      *reinterpret_cast<bf16x8*>(&Bs[n][kq]) = wrow;
    }
    __syncthreads();
    bf16x8 a[4], b[2];
#pragma unroll
    for (int mf = 0; mf < 4; ++mf)
      a[mf] = *reinterpret_cast<const bf16x8*>(&Xs[mf * 16 + lr][lg * 8]);
#pragma unroll
    for (int nf = 0; nf < 2; ++nf)
      b[nf] = *reinterpret_cast<const bf16x8*>(&Bs[wv * 32 + nf * 16 + lr][lg * 8]);
#pragma unroll
    for (int mf = 0; mf < 4; ++mf)
#pragma unroll
      for (int nf = 0; nf < 2; ++nf)
        acc[mf][nf] = __builtin_amdgcn_mfma_f32_16x16x32_bf16(a[mf], b[nf], acc[mf][nf], 0, 0, 0);
    __syncthreads();
  }

  int col[2];
  float bv[2], gv[2], lv[2];
#pragma unroll
  for (int nf = 0; nf < 2; ++nf) {
    col[nf] = wv * 32 + nf * 16 + lr;
    bv[nf] = bias[col[nf]];
    gv[nf] = lng[col[nf]];
    lv[nf] = lnb[col[nf]];
  }

  float z[4][4][2];
#pragma unroll
  for (int mf = 0; mf < 4; ++mf)
#pragma unroll
    for (int reg = 0; reg < 4; ++reg) {
      float z0 = acc[mf][0][reg] + bv[0];
      float z1 = acc[mf][1][reg] + bv[1];
      z[mf][reg][0] = z0;
      z[mf][reg][1] = z1;
      float s = z0 + z1;
      float q = z0 * z0 + z1 * z1;
#pragma unroll
      for (int m = 1; m < 16; m <<= 1) {
        s += __shfl_xor(s, m);
        q += __shfl_xor(q, m);
      }
      if (lr == 0) {
        sredS[mf * 16 + lg * 4 + reg][wv] = s;
        sredQ[mf * 16 + lg * 4 + reg][wv] = q;
      }
    }
  __syncthreads();
#pragma unroll
  for (int mf = 0; mf < 4; ++mf)
#pragma unroll
    for (int reg = 0; reg < 4; ++reg) {
      int tr = mf * 16 + lg * 4 + reg;
      f32x4 S4 = *reinterpret_cast<const f32x4*>(&sredS[tr][0]);
      f32x4 Q4 = *reinterpret_cast<const f32x4*>(&sredQ[tr][0]);
      float S = S4[0] + S4[1] + S4[2] + S4[3];
      float Q = Q4[0] + Q4[1] + Q4[2] + Q4[3];
      float mean = S * (1.f / 128.f);
      float var = Q * (1.f / 128.f) - mean * mean;
      float rstd = rsqrtf(var + LN_EPS);
      int grow = row0 + tr;
      if (grow < M) {
#pragma unroll
        for (int nf = 0; nf < 2; ++nf) {
          float y = (z[mf][reg][nf] - mean) * rstd * gv[nf] + lv[nf];
          out[(size_t)grow * 128 + col[nf]] = fmaxf(y, 0.f);
        }
      }
    }
}

// ------- MFMA update GEMM (64x128): X = Xcat bf16 [M][256] (agg | base); LN; ReLU -------
__global__ __launch_bounds__(256) void gemm_upd_cat(const unsigned short* __restrict__ Xc,
                                                    const unsigned short* __restrict__ Wbf,
                                                    const float* __restrict__ bias,
                                                    const float* __restrict__ lng,
                                                    const float* __restrict__ lnb,
                                                    float* __restrict__ out, int M) {
  constexpr int K = 256;
  __shared__ unsigned short Xs[64][40];
  __shared__ unsigned short Bs[128][40];
  __shared__ float sredS[64][4];
  __shared__ float sredQ[64][4];
  const int tid = threadIdx.x;
  const int lane = tid & 63, wv = tid >> 6;
  const int lr = lane & 15, lg = lane >> 4;
  const int row0 = blockIdx.x * 64;

  f32x4 acc[4][2];
#pragma unroll
  for (int mf = 0; mf < 4; ++mf)
#pragma unroll
    for (int nf = 0; nf < 2; ++nf) acc[mf][nf] = (f32x4)(0.f);

  for (int k0 = 0; k0 < K; k0 += 32) {
#pragma unroll
    for (int it = 0; it < 2; ++it) {
      int q = tid + it * 256;
      int r = q >> 3, kq = (q & 7) * 4;
      int grow = row0 + r;
      u16x4 p = {0, 0, 0, 0};
      if (grow < M) p = *reinterpret_cast<const u16x4*>(&Xc[(size_t)grow * 256 + k0 + kq]);
      *reinterpret_cast<u16x4*>(&Xs[r][kq]) = p;
    }
#pragma unroll
    for (int it = 0; it < 2; ++it) {
      int q = tid + it * 256;
      int n = q >> 2, kq = (q & 3) * 8;
      bf16x8 wrow = *reinterpret_cast<const bf16x8*>(&Wbf[(size_t)n * K + k0 + kq]);
      *reinterpret_cast<bf16x8*>(&Bs[n][kq]) = wrow;
    }
    __syncthreads();
    bf16x8 a[4], b[2];
#pragma unroll
    for (int mf = 0; mf < 4; ++mf)
      a[mf] = *reinterpret_cast<const bf16x8*>(&Xs[mf * 16 + lr][lg * 8]);
#pragma unroll
    for (int nf = 0; nf < 2; ++nf)
      b[nf] = *reinterpret_cast<const bf16x8*>(&Bs[wv * 32 + nf * 16 + lr][lg * 8]);
#pragma unroll
    for (int mf = 0; mf < 4; ++mf)
#pragma unroll
      for (int nf = 0; nf < 2; ++nf)
        acc[mf][nf] = __builtin_amdgcn_mfma_f32_16x16x32_bf16(a[mf], b[nf], acc[mf][nf], 0, 0, 0);
    __syncthreads();
  }

  int col[2];
  float bv[2], gv[2], lv[2];
#pragma unroll
  for (int nf = 0; nf < 2; ++nf) {
    col[nf] = wv * 32 + nf * 16 + lr;
    bv[nf] = bias[col[nf]];
    gv[nf] = lng[col[nf]];
    lv[nf] = lnb[col[nf]];
  }

  float z[4][4][2];
#pragma unroll
  for (int mf = 0; mf < 4; ++mf)
#pragma unroll
    for (int reg = 0; reg < 4; ++reg) {
      float z0 = acc[mf][0][reg] + bv[0];
      float z1 = acc[mf][1][reg] + bv[1];
      z[mf][reg][0] = z0;
      z[mf][reg][1] = z1;
      float s = z0 + z1;
      float q = z0 * z0 + z1 * z1;
#pragma unroll
      for (int m = 1; m < 16; m <<= 1) {
        s += __shfl_xor(s, m);
        q += __shfl_xor(q, m);
      }
      if (lr == 0) {
        sredS[mf * 16 + lg * 4 + reg][wv] = s;
        sredQ[mf * 16 + lg * 4 + reg][wv] = q;
      }
    }
  __syncthreads();
#pragma unroll
  for (int mf = 0; mf < 4; ++mf)
#pragma unroll
    for (int reg = 0; reg < 4; ++reg) {
      int tr = mf * 16 + lg * 4 + reg;
      f32x4 S4 = *reinterpret_cast<const f32x4*>(&sredS[tr][0]);
      f32x4 Q4 = *reinterpret_cast<const f32x4*>(&sredQ[tr][0]);
      float S = S4[0] + S4[1] + S4[2] + S4[3];
      float Q = Q4[0] + Q4[1] + Q4[2] + Q4[3];
      float mean = S * (1.f / 128.f);
      float var = Q * (1.f / 128.f) - mean * mean;
      float rstd = rsqrtf(var + LN_EPS);
      int grow = row0 + tr;
      if (grow < M) {
#pragma unroll
        for (int nf = 0; nf < 2; ++nf) {
          float y = (z[mf][reg][nf] - mean) * rstd * gv[nf] + lv[nf];
          out[(size_t)grow * 128 + col[nf]] = fmaxf(y, 0.f);
        }
      }
    }
}

extern "C" void kernel_launch(void* const* d_in, const int* in_sizes, int n_in,
                              void* d_out, int out_size, void* d_ws, size_t ws_size,
                              hipStream_t stream) {
  const float* vh = (const float*)d_in[0];
  const float* ch = (const float*)d_in[1];
  const int* ei = (const int*)d_in[2];   // [ci(E), vi(E)]
  const float* ew = (const float*)d_in[3];
  const float* v2c_lin_w = (const float*)d_in[4];
  const float* v2c_lin_b = (const float*)d_in[5];
  const float* v2c_gate_w = (const float*)d_in[6];
  const float* v2c_gate_b = (const float*)d_in[7];
  const float* v2c_upd_w = (const float*)d_in[8];
  const float* v2c_upd_b = (const float*)d_in[9];
  const float* v2c_ln_g = (const float*)d_in[10];
  const float* v2c_ln_b = (const float*)d_in[11];
  const float* c2v_lin_w = (const float*)d_in[12];
  const float* c2v_lin_b = (const float*)d_in[13];
  const float* c2v_gate_w = (const float*)d_in[14];
  const float* c2v_gate_b = (const float*)d_in[15];
  const float* c2v_upd_w = (const float*)d_in[16];
  const float* c2v_upd_b = (const float*)d_in[17];
  const float* c2v_ln_g = (const float*)d_in[18];
  const float* c2v_ln_b = (const float*)d_in[19];

  const int N = in_sizes[0] / 128;
  const int C = in_sizes[1] / 128;
  const int E = in_sizes[3];
  const int* ci = ei;
  const int* vi = ei + E;

  // ---- workspace layout (u16 units) ----
  unsigned short* Xcat = (unsigned short*)d_ws;         // N*256: [agg_v|tmp_v] cols 0-127, bf16(vh) cols 128-255
  unsigned short* aggC = Xcat + (size_t)N * 256;        // C*128: agg_c, later tmp_c
  unsigned short* wbf = aggC + (size_t)C * 128;         // 98304
  unsigned short* wbfLinV = wbf;
  unsigned short* wbfUpdV = wbf + 16384;
  unsigned short* wbfLinC = wbf + 49152;
  unsigned short* wbfUpdC = wbf + 65536;
  int* offC = (int*)(wbf + 98304);                      // C+1
  int* offV = offC + (C + 1);                           // N+1
  size_t ofs = (size_t)((offV + (N + 1)) - (int*)d_ws);
  ofs = (ofs + 1) & ~(size_t)1;                         // 8B align
  int2* edataC = (int2*)((int*)d_ws + ofs);             // E
  int2* edataV = edataC + E;                            // E
  // sort scratch aliased into aggC (dead until seg v2c writes it)
  int* cntC = (int*)aggC;                               // C
  int* cntV = cntC + C;                                 // N
  int* bsumS = cntV + N;                                // 1024
  int* curC = bsumS + 1024;                             // C
  int* curV = curC + C;                                 // N

  float* vhNew = (float*)d_out;
  float* chNew = (float*)d_out + (size_t)N * 128;

  // weights f32->bf16 (one launch)
  cvt4_bf16<<<(98304 + 255) / 256, 256, 0, stream>>>(v2c_lin_w, v2c_upd_w, c2v_lin_w,
                                                     c2v_upd_w, wbfLinV, wbfUpdV, wbfLinC,
                                                     wbfUpdC);

  const int egrid = (E + 255) / 256;

  // ---- counting sorts (fused hist + fused reorder; scan3 fills cursors) ----
  hipMemsetAsync(cntC, 0, (size_t)(C + N) * sizeof(int), stream);
  hist2_kernel<<<egrid, 256, 0, stream>>>(ci, vi, cntC, cntV, E);
  {
    int nb = (C + 1023) / 1024;
    scan1<<<nb, 256, 0, stream>>>(cntC, offC, bsumS, C);
    scan2<<<1, 256, 0, stream>>>(bsumS, nb);
    scan3<<<(C + 1 + 255) / 256, 256, 0, stream>>>(offC, curC, bsumS, C, E);
  }
  {
    int nb = (N + 1023) / 1024;
    scan1<<<nb, 256, 0, stream>>>(cntV, offV, bsumS, N);
    scan2<<<1, 256, 0, stream>>>(bsumS, nb);
    scan3<<<(N + 1 + 255) / 256, 256, 0, stream>>>(offV, curV, bsumS, N, E);
  }
  reorder2_kernel<<<egrid, 256, 0, stream>>>(ci, vi, ew, curC, curV, edataC, edataV, E);

  // ---- v2c ----
  // lin: tmp_v -> Xcat[:,0:128]; bf16(vh) -> Xcat[:,128:256]
  gemm_lin_mfma<128, 256, true><<<(N + 63) / 64, 256, 0, stream>>>(vh, wbfLinV, v2c_lin_b,
                                                                   Xcat, Xcat, N);
  seg_reduce<<<(C + 3) / 4, 256, 0, stream>>>(offC, edataC, v2c_gate_w, v2c_gate_b,
                                              Xcat, 256, aggC, 128, C);
  gemm_upd_mix<<<(C + 63) / 64, 256, 0, stream>>>(aggC, ch, wbfUpdV, v2c_upd_b,
                                                  v2c_ln_g, v2c_ln_b, chNew, C);

  // ---- c2v ----
  unsigned short* tmpC = aggC;   // reuse (agg_c dead after upd_mix)
  gemm_lin_mfma<128, 128, false><<<(C + 63) / 64, 256, 0, stream>>>(chNew, wbfLinC,
                                                                    c2v_lin_b, tmpC,
                                                                    nullptr, C);
  // agg_v written over tmp_v in Xcat[:,0:128] (tmp_v dead after v2c seg_reduce)
  seg_reduce<<<(N + 3) / 4, 256, 0, stream>>>(offV, edataV, c2v_gate_w, c2v_gate_b,
                                              tmpC, 128, Xcat, 256, N);
  gemm_upd_cat<<<(N + 63) / 64, 256, 0, stream>>>(Xcat, wbfUpdC, c2v_upd_b,
                                                  c2v_ln_g, c2v_ln_b, vhNew, N);
}

// Round 7
// 355.027 us; speedup vs baseline: 1.2208x; 1.1811x over previous
//
#include <hip/hip_runtime.h>

#define LN_EPS 1e-5f

typedef float f32x4 __attribute__((ext_vector_type(4)));
typedef short bf16x8 __attribute__((ext_vector_type(8)));
typedef unsigned short u16x4 __attribute__((ext_vector_type(4)));

__device__ __forceinline__ unsigned short f2bf(float f) {
  unsigned int u = __float_as_uint(f);
  u = (u + 0x7fffu + ((u >> 16) & 1u)) >> 16;
  return (unsigned short)u;
}
__device__ __forceinline__ float bf2f(unsigned short h) {
  return __uint_as_float((unsigned int)h << 16);
}
__device__ __forceinline__ float sigm(float x) {
  return 1.f / (1.f + __expf(-x));
}

// ---------------- fused f32 -> bf16 convert for all 4 weight mats ----------------
__global__ __launch_bounds__(256) void cvt4_bf16(const float* __restrict__ a,
                                                 const float* __restrict__ b,
                                                 const float* __restrict__ c,
                                                 const float* __restrict__ d,
                                                 unsigned short* __restrict__ oa,
                                                 unsigned short* __restrict__ ob,
                                                 unsigned short* __restrict__ oc,
                                                 unsigned short* __restrict__ od) {
  int i = blockIdx.x * 256 + threadIdx.x;
  if (i < 16384) oa[i] = f2bf(a[i]);
  else if (i < 49152) ob[i - 16384] = f2bf(b[i - 16384]);
  else if (i < 65536) oc[i - 49152] = f2bf(c[i - 49152]);
  else if (i < 98304) od[i - 65536] = f2bf(d[i - 65536]);
}

// ------- fused histogram + rank: rank = atomicAdd return (order within bucket) -------
// 4 edges per thread, stride-separated for coalescing; independent atomic chains.
__global__ __launch_bounds__(256) void hist2_rank(const int* __restrict__ ci,
                                                  const int* __restrict__ vi,
                                                  int* __restrict__ cntC,
                                                  int* __restrict__ cntV,
                                                  int* __restrict__ rankC,
                                                  int* __restrict__ rankV, int E) {
  int tid = blockIdx.x * 256 + threadIdx.x;
  int T = gridDim.x * 256;
  int e[4], c[4], v[4];
  bool ok[4];
#pragma unroll
  for (int i = 0; i < 4; ++i) {
    e[i] = tid + i * T;
    ok[i] = e[i] < E;
  }
#pragma unroll
  for (int i = 0; i < 4; ++i) if (ok[i]) c[i] = ci[e[i]];
#pragma unroll
  for (int i = 0; i < 4; ++i) if (ok[i]) v[i] = vi[e[i]];
  int rc[4], rv[4];
#pragma unroll
  for (int i = 0; i < 4; ++i) if (ok[i]) rc[i] = atomicAdd(&cntC[c[i]], 1);
#pragma unroll
  for (int i = 0; i < 4; ++i) if (ok[i]) rv[i] = atomicAdd(&cntV[v[i]], 1);
#pragma unroll
  for (int i = 0; i < 4; ++i) if (ok[i]) rankC[e[i]] = rc[i];
#pragma unroll
  for (int i = 0; i < 4; ++i) if (ok[i]) rankV[e[i]] = rv[i];
}

__global__ __launch_bounds__(256) void scan1(const int* __restrict__ cnt,
                                             int* __restrict__ off,
                                             int* __restrict__ bsum, int M) {
  __shared__ int s[256];
  int base = blockIdx.x * 1024 + threadIdx.x * 4;
  int v[4];
  int tot = 0;
#pragma unroll
  for (int i = 0; i < 4; ++i) {
    int idx = base + i;
    v[i] = (idx < M) ? cnt[idx] : 0;
    tot += v[i];
  }
  s[threadIdx.x] = tot;
  __syncthreads();
  for (int d = 1; d < 256; d <<= 1) {
    int t = (threadIdx.x >= d) ? s[threadIdx.x - d] : 0;
    __syncthreads();
    s[threadIdx.x] += t;
    __syncthreads();
  }
  int excl = s[threadIdx.x] - tot;
#pragma unroll
  for (int i = 0; i < 4; ++i) {
    int idx = base + i;
    if (idx < M) off[idx] = excl;
    excl += v[i];
  }
  if (threadIdx.x == 255) bsum[blockIdx.x] = s[255];
}

__global__ __launch_bounds__(256) void scan2(int* __restrict__ bsum, int nb) {
  __shared__ int s[256];
  __shared__ int carry;
  if (threadIdx.x == 0) carry = 0;
  __syncthreads();
  for (int base = 0; base < nb; base += 256) {
    int idx = base + threadIdx.x;
    int v = (idx < nb) ? bsum[idx] : 0;
    s[threadIdx.x] = v;
    __syncthreads();
    for (int d = 1; d < 256; d <<= 1) {
      int t = (threadIdx.x >= d) ? s[threadIdx.x - d] : 0;
      __syncthreads();
      s[threadIdx.x] += t;
      __syncthreads();
    }
    if (idx < nb) bsum[idx] = s[threadIdx.x] - v + carry;
    __syncthreads();
    if (threadIdx.x == 0) carry += s[255];
    __syncthreads();
  }
}

__global__ __launch_bounds__(256) void scan3(int* __restrict__ off,
                                             const int* __restrict__ bsum, int M, int E) {
  int idx = blockIdx.x * 256 + threadIdx.x;
  if (idx < M) off[idx] += bsum[idx >> 10];
  if (idx == M) off[M] = E;
}

// ------- scatter (no atomics): pos = off[dest] + rank; 4 edges/thread -------
__global__ __launch_bounds__(256) void scatter2_kernel(const int* __restrict__ ci,
                                                       const int* __restrict__ vi,
                                                       const float* __restrict__ ew,
                                                       const int* __restrict__ offC,
                                                       const int* __restrict__ offV,
                                                       const int* __restrict__ rankC,
                                                       const int* __restrict__ rankV,
                                                       int2* __restrict__ edataC,
                                                       int2* __restrict__ edataV, int E) {
  int tid = blockIdx.x * 256 + threadIdx.x;
  int T = gridDim.x * 256;
  int e[4], c[4], v[4], wb[4], rc[4], rv[4];
  bool ok[4];
#pragma unroll
  for (int i = 0; i < 4; ++i) {
    e[i] = tid + i * T;
    ok[i] = e[i] < E;
  }
#pragma unroll
  for (int i = 0; i < 4; ++i) if (ok[i]) c[i] = ci[e[i]];
#pragma unroll
  for (int i = 0; i < 4; ++i) if (ok[i]) v[i] = vi[e[i]];
#pragma unroll
  for (int i = 0; i < 4; ++i) if (ok[i]) wb[i] = __float_as_int(ew[e[i]]);
#pragma unroll
  for (int i = 0; i < 4; ++i) if (ok[i]) rc[i] = rankC[e[i]];
#pragma unroll
  for (int i = 0; i < 4; ++i) if (ok[i]) rv[i] = rankV[e[i]];
  int pc[4], pv[4];
#pragma unroll
  for (int i = 0; i < 4; ++i) if (ok[i]) pc[i] = offC[c[i]] + rc[i];
#pragma unroll
  for (int i = 0; i < 4; ++i) if (ok[i]) pv[i] = offV[v[i]] + rv[i];
#pragma unroll
  for (int i = 0; i < 4; ++i) if (ok[i]) edataC[pc[i]] = make_int2(v[i], wb[i]);
#pragma unroll
  for (int i = 0; i < 4; ++i) if (ok[i]) edataV[pv[i]] = make_int2(c[i], wb[i]);
}

// ---------------- segmented gather*gate reduce -> mean (bf16 src/out) ----------------
// 256-thread block = 4 waves; wave w handles segment blockIdx.x*4+w; lane j: cols 2j,2j+1
__global__ __launch_bounds__(256) void seg_reduce(const int* __restrict__ off,
                                                  const int2* __restrict__ edata,
                                                  const float* __restrict__ gw,
                                                  const float* __restrict__ gb,
                                                  const unsigned short* __restrict__ src,
                                                  int srcStride,
                                                  unsigned short* __restrict__ out,
                                                  int outStride, int M) {
  int seg = blockIdx.x * 4 + (threadIdx.x >> 6);
  if (seg >= M) return;
  int j = threadIdx.x & 63;
  int start = off[seg], end = off[seg + 1];
  float gwa = gw[2 * j], gwb = gw[2 * j + 1];
  float gba = gb[2 * j], gbb = gb[2 * j + 1];
  float a0 = 0.f, a1 = 0.f;
  int p = start;
  for (; p + 4 <= end; p += 4) {
    int2 e0 = edata[p], e1 = edata[p + 1], e2 = edata[p + 2], e3 = edata[p + 3];
    unsigned int v0 = *reinterpret_cast<const unsigned int*>(&src[(size_t)e0.x * srcStride + 2 * j]);
    unsigned int v1 = *reinterpret_cast<const unsigned int*>(&src[(size_t)e1.x * srcStride + 2 * j]);
    unsigned int v2 = *reinterpret_cast<const unsigned int*>(&src[(size_t)e2.x * srcStride + 2 * j]);
    unsigned int v3 = *reinterpret_cast<const unsigned int*>(&src[(size_t)e3.x * srcStride + 2 * j]);
    float w0 = __int_as_float(e0.y), w1 = __int_as_float(e1.y);
    float w2 = __int_as_float(e2.y), w3 = __int_as_float(e3.y);
    a0 += bf2f((unsigned short)(v0 & 0xffff)) * sigm(w0 * gwa + gba)
        + bf2f((unsigned short)(v1 & 0xffff)) * sigm(w1 * gwa + gba)
        + bf2f((unsigned short)(v2 & 0xffff)) * sigm(w2 * gwa + gba)
        + bf2f((unsigned short)(v3 & 0xffff)) * sigm(w3 * gwa + gba);
    a1 += bf2f((unsigned short)(v0 >> 16)) * sigm(w0 * gwb + gbb)
        + bf2f((unsigned short)(v1 >> 16)) * sigm(w1 * gwb + gbb)
        + bf2f((unsigned short)(v2 >> 16)) * sigm(w2 * gwb + gbb)
        + bf2f((unsigned short)(v3 >> 16)) * sigm(w3 * gwb + gbb);
  }
  if (p + 2 <= end) {
    int2 e0 = edata[p], e1 = edata[p + 1];
    unsigned int v0 = *reinterpret_cast<const unsigned int*>(&src[(size_t)e0.x * srcStride + 2 * j]);
    unsigned int v1 = *reinterpret_cast<const unsigned int*>(&src[(size_t)e1.x * srcStride + 2 * j]);
    float w0 = __int_as_float(e0.y), w1 = __int_as_float(e1.y);
    a0 += bf2f((unsigned short)(v0 & 0xffff)) * sigm(w0 * gwa + gba)
        + bf2f((unsigned short)(v1 & 0xffff)) * sigm(w1 * gwa + gba);
    a1 += bf2f((unsigned short)(v0 >> 16)) * sigm(w0 * gwb + gbb)
        + bf2f((unsigned short)(v1 >> 16)) * sigm(w1 * gwb + gbb);
    p += 2;
  }
  if (p < end) {
    int2 e0 = edata[p];
    unsigned int v0 = *reinterpret_cast<const unsigned int*>(&src[(size_t)e0.x * srcStride + 2 * j]);
    float w0 = __int_as_float(e0.y);
    a0 += bf2f((unsigned short)(v0 & 0xffff)) * sigm(w0 * gwa + gba);
    a1 += bf2f((unsigned short)(v0 >> 16)) * sigm(w0 * gwb + gbb);
  }
  int cnt = end - start;
  float inv = 1.f / (float)(cnt > 1 ? cnt : 1);
  unsigned int packed = (unsigned int)f2bf(a0 * inv) | ((unsigned int)f2bf(a1 * inv) << 16);
  *reinterpret_cast<unsigned int*>(&out[(size_t)seg * outStride + 2 * j]) = packed;
}

// ------- MFMA GEMM (64x128 tile): out bf16 = bf16(X f32) @ Wbf^T + bias -------
// OS: output row stride. WBF: also store the staged bf16(X) tile to bfdst[:,128:256] (Xcat).
template <int K, int OS, bool WBF>
__global__ __launch_bounds__(256) void gemm_lin_mfma(const float* __restrict__ X,
                                                     const unsigned short* __restrict__ Wbf,
                                                     const float* __restrict__ bias,
                                                     unsigned short* __restrict__ out,
                                                     unsigned short* __restrict__ bfdst,
                                                     int M) {
  __shared__ unsigned short Xs[64][40];   // 80B row stride: conflict-free b128 reads
  __shared__ unsigned short Bs[128][40];
  const int tid = threadIdx.x;
  const int lane = tid & 63, wv = tid >> 6;
  const int lr = lane & 15, lg = lane >> 4;
  const int row0 = blockIdx.x * 64;

  f32x4 acc[4][2];
#pragma unroll
  for (int mf = 0; mf < 4; ++mf)
#pragma unroll
    for (int nf = 0; nf < 2; ++nf) acc[mf][nf] = (f32x4)(0.f);

  for (int k0 = 0; k0 < K; k0 += 32) {
#pragma unroll
    for (int it = 0; it < 2; ++it) {
      int q = tid + it * 256;
      int r = q >> 3, kq = (q & 7) * 4;
      int grow = row0 + r;
      float4 v = make_float4(0.f, 0.f, 0.f, 0.f);
      if (grow < M) v = *reinterpret_cast<const float4*>(&X[(size_t)grow * K + k0 + kq]);
      u16x4 p = {f2bf(v.x), f2bf(v.y), f2bf(v.z), f2bf(v.w)};
      *reinterpret_cast<u16x4*>(&Xs[r][kq]) = p;
      if (WBF && grow < M)
        *reinterpret_cast<u16x4*>(&bfdst[(size_t)grow * 256 + 128 + k0 + kq]) = p;
    }
#pragma unroll
    for (int it = 0; it < 2; ++it) {
      int q = tid + it * 256;
      int n = q >> 2, kq = (q & 3) * 8;
      bf16x8 wrow = *reinterpret_cast<const bf16x8*>(&Wbf[(size_t)n * K + k0 + kq]);
      *reinterpret_cast<bf16x8*>(&Bs[n][kq]) = wrow;
    }
    __syncthreads();
    bf16x8 a[4], b[2];
#pragma unroll
    for (int mf = 0; mf < 4; ++mf)
      a[mf] = *reinterpret_cast<const bf16x8*>(&Xs[mf * 16 + lr][lg * 8]);
#pragma unroll
    for (int nf = 0; nf < 2; ++nf)
      b[nf] = *reinterpret_cast<const bf16x8*>(&Bs[wv * 32 + nf * 16 + lr][lg * 8]);
#pragma unroll
    for (int mf = 0; mf < 4; ++mf)
#pragma unroll
      for (int nf = 0; nf < 2; ++nf)
        acc[mf][nf] = __builtin_amdgcn_mfma_f32_16x16x32_bf16(a[mf], b[nf], acc[mf][nf], 0, 0, 0);
    __syncthreads();
  }

  int col[2];
  float bv[2];
#pragma unroll
  for (int nf = 0; nf < 2; ++nf) {
    col[nf] = wv * 32 + nf * 16 + lr;
    bv[nf] = bias[col[nf]];
  }
#pragma unroll
  for (int mf = 0; mf < 4; ++mf)
#pragma unroll
    for (int reg = 0; reg < 4; ++reg) {
      int grow = row0 + mf * 16 + lg * 4 + reg;
      if (grow < M) {
#pragma unroll
        for (int nf = 0; nf < 2; ++nf)
          out[(size_t)grow * OS + col[nf]] = f2bf(acc[mf][nf][reg] + bv[nf]);
      }
    }
}

// ------- MFMA update GEMM (64x128): X = concat(agg bf16, base f32); LN; ReLU ----
__global__ __launch_bounds__(256) void gemm_upd_mix(const unsigned short* __restrict__ agg,
                                                    const float* __restrict__ base,
                                                    const unsigned short* __restrict__ Wbf,
                                                    const float* __restrict__ bias,
                                                    const float* __restrict__ lng,
                                                    const float* __restrict__ lnb,
                                                    float* __restrict__ out, int M) {
  constexpr int K = 256;
  __shared__ unsigned short Xs[64][40];
  __shared__ unsigned short Bs[128][40];
  __shared__ float sredS[64][4];
  __shared__ float sredQ[64][4];
  const int tid = threadIdx.x;
  const int lane = tid & 63, wv = tid >> 6;
  const int lr = lane & 15, lg = lane >> 4;
  const int row0 = blockIdx.x * 64;

  f32x4 acc[4][2];
#pragma unroll
  for (int mf = 0; mf < 4; ++mf)
#pragma unroll
    for (int nf = 0; nf < 2; ++nf) acc[mf][nf] = (f32x4)(0.f);

  for (int k0 = 0; k0 < K; k0 += 32) {
#pragma unroll
    for (int it = 0; it < 2; ++it) {
      int q = tid + it * 256;
      int r = q >> 3, kq = (q & 7) * 4;
      int grow = row0 + r, gk = k0 + kq;
      u16x4 p = {0, 0, 0, 0};
      if (grow < M) {
        if (gk < 128) {
          p = *reinterpret_cast<const u16x4*>(&agg[(size_t)grow * 128 + gk]);
        } else {
          float4 v = *reinterpret_cast<const float4*>(&base[(size_t)grow * 128 + (gk - 128)]);
          p = {f2bf(v.x), f2bf(v.y), f2bf(v.z), f2bf(v.w)};
        }
      }
      *reinterpret_cast<u16x4*>(&Xs[r][kq]) = p;
    }
#pragma unroll
    for (int it = 0; it < 2; ++it) {
      int q = tid + it * 256;
      int n = q >> 2, kq = (q & 3) * 8;
      bf16x8 wrow = *reinterpret_cast<const bf16x8*>(&Wbf[(size_t)n * K + k0 + kq]);
      *reinterpret_cast<bf16x8*>(&Bs[n][kq]) = wrow;
    }
    __syncthreads();
    bf16x8 a[4], b[2];
#pragma unroll
    for (int mf = 0; mf < 4; ++mf)
      a[mf] = *reinterpret_cast<const bf16x8*>(&Xs[mf * 16 + lr][lg * 8]);
#pragma unroll
    for (int nf = 0; nf < 2; ++nf)
      b[nf] = *reinterpret_cast<const bf16x8*>(&Bs[wv * 32 + nf * 16 + lr][lg * 8]);
#pragma unroll
    for (int mf = 0; mf < 4; ++mf)
#pragma unroll
      for (int nf = 0; nf < 2; ++nf)
        acc[mf][nf] = __builtin_amdgcn_mfma_f32_16x16x32_bf16(a[mf], b[nf], acc[mf][nf], 0, 0, 0);
    __syncthreads();
  }

  int col[2];
  float bv[2], gv[2], lv[2];
#pragma unroll
  for (int nf = 0; nf < 2; ++nf) {
    col[nf] = wv * 32 + nf * 16 + lr;
    bv[nf] = bias[col[nf]];
    gv[nf] = lng[col[nf]];
    lv[nf] = lnb[col[nf]];
  }

  float z[4][4][2];
#pragma unroll
  for (int mf = 0; mf < 4; ++mf)
#pragma unroll
    for (int reg = 0; reg < 4; ++reg) {
      float z0 = acc[mf][0][reg] + bv[0];
      float z1 = acc[mf][1][reg] + bv[1];
      z[mf][reg][0] = z0;
      z[mf][reg][1] = z1;
      float s = z0 + z1;
      float q = z0 * z0 + z1 * z1;
#pragma unroll
      for (int m = 1; m < 16; m <<= 1) {
        s += __shfl_xor(s, m);
        q += __shfl_xor(q, m);
      }
      if (lr == 0) {
        sredS[mf * 16 + lg * 4 + reg][wv] = s;
        sredQ[mf * 16 + lg * 4 + reg][wv] = q;
      }
    }
  __syncthreads();
#pragma unroll
  for (int mf = 0; mf < 4; ++mf)
#pragma unroll
    for (int reg = 0; reg < 4; ++reg) {
      int tr = mf * 16 + lg * 4 + reg;
      f32x4 S4 = *reinterpret_cast<const f32x4*>(&sredS[tr][0]);
      f32x4 Q4 = *reinterpret_cast<const f32x4*>(&sredQ[tr][0]);
      float S = S4[0] + S4[1] + S4[2] + S4[3];
      float Q = Q4[0] + Q4[1] + Q4[2] + Q4[3];
      float mean = S * (1.f / 128.f);
      float var = Q * (1.f / 128.f) - mean * mean;
      float rstd = rsqrtf(var + LN_EPS);
      int grow = row0 + tr;
      if (grow < M) {
#pragma unroll
        for (int nf = 0; nf < 2; ++nf) {
          float y = (z[mf][reg][nf] - mean) * rstd * gv[nf] + lv[nf];
          out[(size_t)grow * 128 + col[nf]] = fmaxf(y, 0.f);
        }
      }
    }
}

// ------- MFMA update GEMM (64x128): X = Xcat bf16 [M][256] (agg | base); LN; ReLU -------
__global__ __launch_bounds__(256) void gemm_upd_cat(const unsigned short* __restrict__ Xc,
                                                    const unsigned short* __restrict__ Wbf,
                                                    const float* __restrict__ bias,
                                                    const float* __restrict__ lng,
                                                    const float* __restrict__ lnb,
                                                    float* __restrict__ out, int M) {
  constexpr int K = 256;
  __shared__ unsigned short Xs[64][40];
  __shared__ unsigned short Bs[128][40];
  __shared__ float sredS[64][4];
  __shared__ float sredQ[64][4];
  const int tid = threadIdx.x;
  const int lane = tid & 63, wv = tid >> 6;
  const int lr = lane & 15, lg = lane >> 4;
  const int row0 = blockIdx.x * 64;

  f32x4 acc[4][2];
#pragma unroll
  for (int mf = 0; mf < 4; ++mf)
#pragma unroll
    for (int nf = 0; nf < 2; ++nf) acc[mf][nf] = (f32x4)(0.f);

  for (int k0 = 0; k0 < K; k0 += 32) {
#pragma unroll
    for (int it = 0; it < 2; ++it) {
      int q = tid + it * 256;
      int r = q >> 3, kq = (q & 7) * 4;
      int grow = row0 + r;
      u16x4 p = {0, 0, 0, 0};
      if (grow < M) p = *reinterpret_cast<const u16x4*>(&Xc[(size_t)grow * 256 + k0 + kq]);
      *reinterpret_cast<u16x4*>(&Xs[r][kq]) = p;
    }
#pragma unroll
    for (int it = 0; it < 2; ++it) {
      int q = tid + it * 256;
      int n = q >> 2, kq = (q & 3) * 8;
      bf16x8 wrow = *reinterpret_cast<const bf16x8*>(&Wbf[(size_t)n * K + k0 + kq]);
      *reinterpret_cast<bf16x8*>(&Bs[n][kq]) = wrow;
    }
    __syncthreads();
    bf16x8 a[4], b[2];
#pragma unroll
    for (int mf = 0; mf < 4; ++mf)
      a[mf] = *reinterpret_cast<const bf16x8*>(&Xs[mf * 16 + lr][lg * 8]);
#pragma unroll
    for (int nf = 0; nf < 2; ++nf)
      b[nf] = *reinterpret_cast<const bf16x8*>(&Bs[wv * 32 + nf * 16 + lr][lg * 8]);
#pragma unroll
    for (int mf = 0; mf < 4; ++mf)
#pragma unroll
      for (int nf = 0; nf < 2; ++nf)
        acc[mf][nf] = __builtin_amdgcn_mfma_f32_16x16x32_bf16(a[mf], b[nf], acc[mf][nf], 0, 0, 0);
    __syncthreads();
  }

  int col[2];
  float bv[2], gv[2], lv[2];
#pragma unroll
  for (int nf = 0; nf < 2; ++nf) {
    col[nf] = wv * 32 + nf * 16 + lr;
    bv[nf] = bias[col[nf]];
    gv[nf] = lng[col[nf]];
    lv[nf] = lnb[col[nf]];
  }

  float z[4][4][2];
#pragma unroll
  for (int mf = 0; mf < 4; ++mf)
#pragma unroll
    for (int reg = 0; reg < 4; ++reg) {
      float z0 = acc[mf][0][reg] + bv[0];
      float z1 = acc[mf][1][reg] + bv[1];
      z[mf][reg][0] = z0;
      z[mf][reg][1] = z1;
      float s = z0 + z1;
      float q = z0 * z0 + z1 * z1;
#pragma unroll
      for (int m = 1; m < 16; m <<= 1) {
        s += __shfl_xor(s, m);
        q += __shfl_xor(q, m);
      }
      if (lr == 0) {
        sredS[mf * 16 + lg * 4 + reg][wv] = s;
        sredQ[mf * 16 + lg * 4 + reg][wv] = q;
      }
    }
  __syncthreads();
#pragma unroll
  for (int mf = 0; mf < 4; ++mf)
#pragma unroll
    for (int reg = 0; reg < 4; ++reg) {
      int tr = mf * 16 + lg * 4 + reg;
      f32x4 S4 = *reinterpret_cast<const f32x4*>(&sredS[tr][0]);
      f32x4 Q4 = *reinterpret_cast<const f32x4*>(&sredQ[tr][0]);
      float S = S4[0] + S4[1] + S4[2] + S4[3];
      float Q = Q4[0] + Q4[1] + Q4[2] + Q4[3];
      float mean = S * (1.f / 128.f);
      float var = Q * (1.f / 128.f) - mean * mean;
      float rstd = rsqrtf(var + LN_EPS);
      int grow = row0 + tr;
      if (grow < M) {
#pragma unroll
        for (int nf = 0; nf < 2; ++nf) {
          float y = (z[mf][reg][nf] - mean) * rstd * gv[nf] + lv[nf];
          out[(size_t)grow * 128 + col[nf]] = fmaxf(y, 0.f);
        }
      }
    }
}

extern "C" void kernel_launch(void* const* d_in, const int* in_sizes, int n_in,
                              void* d_out, int out_size, void* d_ws, size_t ws_size,
                              hipStream_t stream) {
  const float* vh = (const float*)d_in[0];
  const float* ch = (const float*)d_in[1];
  const int* ei = (const int*)d_in[2];   // [ci(E), vi(E)]
  const float* ew = (const float*)d_in[3];
  const float* v2c_lin_w = (const float*)d_in[4];
  const float* v2c_lin_b = (const float*)d_in[5];
  const float* v2c_gate_w = (const float*)d_in[6];
  const float* v2c_gate_b = (const float*)d_in[7];
  const float* v2c_upd_w = (const float*)d_in[8];
  const float* v2c_upd_b = (const float*)d_in[9];
  const float* v2c_ln_g = (const float*)d_in[10];
  const float* v2c_ln_b = (const float*)d_in[11];
  const float* c2v_lin_w = (const float*)d_in[12];
  const float* c2v_lin_b = (const float*)d_in[13];
  const float* c2v_gate_w = (const float*)d_in[14];
  const float* c2v_gate_b = (const float*)d_in[15];
  const float* c2v_upd_w = (const float*)d_in[16];
  const float* c2v_upd_b = (const float*)d_in[17];
  const float* c2v_ln_g = (const float*)d_in[18];
  const float* c2v_ln_b = (const float*)d_in[19];

  const int N = in_sizes[0] / 128;
  const int C = in_sizes[1] / 128;
  const int E = in_sizes[3];
  const int* ci = ei;
  const int* vi = ei + E;

  // ---- workspace layout (u16 units) ----
  unsigned short* Xcat = (unsigned short*)d_ws;         // N*256: [agg_v|tmp_v] 0-127, bf16(vh) 128-255
  unsigned short* aggC = Xcat + (size_t)N * 256;        // C*128: agg_c, later tmp_c
  unsigned short* wbf = aggC + (size_t)C * 128;         // 98304
  unsigned short* wbfLinV = wbf;
  unsigned short* wbfUpdV = wbf + 16384;
  unsigned short* wbfLinC = wbf + 49152;
  unsigned short* wbfUpdC = wbf + 65536;
  int* offC = (int*)(wbf + 98304);                      // C+1
  int* offV = offC + (C + 1);                           // N+1
  size_t ofs = (size_t)((offV + (N + 1)) - (int*)d_ws);
  ofs = (ofs + 1) & ~(size_t)1;                         // 8B align
  int2* edataC = (int2*)((int*)d_ws + ofs);             // E
  int2* edataV = edataC + E;                            // E
  // sort scratch aliased into aggC (dead until seg v2c writes it):
  //   cntC[C], cntV[N], bsum[1024], rankC[E], rankV[E]  (5.8 MB < 12.8 MB)
  int* cntC = (int*)aggC;
  int* cntV = cntC + C;
  int* bsumS = cntV + N;
  int* rankC = bsumS + 1024;
  int* rankV = rankC + E;

  float* vhNew = (float*)d_out;
  float* chNew = (float*)d_out + (size_t)N * 128;

  // weights f32->bf16 (one launch)
  cvt4_bf16<<<(98304 + 255) / 256, 256, 0, stream>>>(v2c_lin_w, v2c_upd_w, c2v_lin_w,
                                                     c2v_upd_w, wbfLinV, wbfUpdV, wbfLinC,
                                                     wbfUpdC);

  const int egrid4 = (E + 4 * 256 - 1) / (4 * 256);

  // ---- counting sorts: hist+rank -> scans -> scatter (no atomics in scatter) ----
  hipMemsetAsync(cntC, 0, (size_t)(C + N) * sizeof(int), stream);
  hist2_rank<<<egrid4, 256, 0, stream>>>(ci, vi, cntC, cntV, rankC, rankV, E);
  {
    int nb = (C + 1023) / 1024;
    scan1<<<nb, 256, 0, stream>>>(cntC, offC, bsumS, C);
    scan2<<<1, 256, 0, stream>>>(bsumS, nb);
    scan3<<<(C + 1 + 255) / 256, 256, 0, stream>>>(offC, bsumS, C, E);
  }
  {
    int nb = (N + 1023) / 1024;
    scan1<<<nb, 256, 0, stream>>>(cntV, offV, bsumS, N);
    scan2<<<1, 256, 0, stream>>>(bsumS, nb);
    scan3<<<(N + 1 + 255) / 256, 256, 0, stream>>>(offV, bsumS, N, E);
  }
  scatter2_kernel<<<egrid4, 256, 0, stream>>>(ci, vi, ew, offC, offV, rankC, rankV,
                                              edataC, edataV, E);

  // ---- v2c ----
  // lin: tmp_v -> Xcat[:,0:128]; bf16(vh) -> Xcat[:,128:256]
  gemm_lin_mfma<128, 256, true><<<(N + 63) / 64, 256, 0, stream>>>(vh, wbfLinV, v2c_lin_b,
                                                                   Xcat, Xcat, N);
  seg_reduce<<<(C + 3) / 4, 256, 0, stream>>>(offC, edataC, v2c_gate_w, v2c_gate_b,
                                              Xcat, 256, aggC, 128, C);
  gemm_upd_mix<<<(C + 63) / 64, 256, 0, stream>>>(aggC, ch, wbfUpdV, v2c_upd_b,
                                                  v2c_ln_g, v2c_ln_b, chNew, C);

  // ---- c2v ----
  unsigned short* tmpC = aggC;   // reuse (agg_c dead after upd_mix)
  gemm_lin_mfma<128, 128, false><<<(C + 63) / 64, 256, 0, stream>>>(chNew, wbfLinC,
                                                                    c2v_lin_b, tmpC,
                                                                    nullptr, C);
  // agg_v written over tmp_v in Xcat[:,0:128] (tmp_v dead after v2c seg_reduce)
  seg_reduce<<<(N + 3) / 4, 256, 0, stream>>>(offV, edataV, c2v_gate_w, c2v_gate_b,
                                              tmpC, 128, Xcat, 256, N);
  gemm_upd_cat<<<(N + 63) / 64, 256, 0, stream>>>(Xcat, wbfUpdC, c2v_upd_b,
                                                  c2v_ln_g, c2v_ln_b, vhNew, N);
}

// Round 8
// 336.845 us; speedup vs baseline: 1.2867x; 1.0540x over previous
//
#include <hip/hip_runtime.h>

#define LN_EPS 1e-5f

typedef float f32x4 __attribute__((ext_vector_type(4)));
typedef short bf16x8 __attribute__((ext_vector_type(8)));
typedef unsigned short u16x4 __attribute__((ext_vector_type(4)));

__device__ __forceinline__ unsigned short f2bf(float f) {
  unsigned int u = __float_as_uint(f);
  u = (u + 0x7fffu + ((u >> 16) & 1u)) >> 16;
  return (unsigned short)u;
}
__device__ __forceinline__ float bf2f(unsigned short h) {
  return __uint_as_float((unsigned int)h << 16);
}
__device__ __forceinline__ float sigm(float x) {
  return 1.f / (1.f + __expf(-x));
}

// ---------------- fused f32 -> bf16 convert for all 4 weight mats ----------------
__global__ __launch_bounds__(256) void cvt4_bf16(const float* __restrict__ a,
                                                 const float* __restrict__ b,
                                                 const float* __restrict__ c,
                                                 const float* __restrict__ d,
                                                 unsigned short* __restrict__ oa,
                                                 unsigned short* __restrict__ ob,
                                                 unsigned short* __restrict__ oc,
                                                 unsigned short* __restrict__ od) {
  int i = blockIdx.x * 256 + threadIdx.x;
  if (i < 16384) oa[i] = f2bf(a[i]);
  else if (i < 49152) ob[i - 16384] = f2bf(b[i - 16384]);
  else if (i < 65536) oc[i - 49152] = f2bf(c[i - 49152]);
  else if (i < 98304) od[i - 65536] = f2bf(d[i - 65536]);
}

// ------- fused histogram + rank: rank = atomicAdd return (order within bucket) -------
__global__ __launch_bounds__(256) void hist2_rank(const int* __restrict__ ci,
                                                  const int* __restrict__ vi,
                                                  int* __restrict__ cntC,
                                                  int* __restrict__ cntV,
                                                  int* __restrict__ rankC,
                                                  int* __restrict__ rankV, int E) {
  int tid = blockIdx.x * 256 + threadIdx.x;
  int T = gridDim.x * 256;
  int e[4], c[4], v[4];
  bool ok[4];
#pragma unroll
  for (int i = 0; i < 4; ++i) {
    e[i] = tid + i * T;
    ok[i] = e[i] < E;
  }
#pragma unroll
  for (int i = 0; i < 4; ++i) if (ok[i]) c[i] = ci[e[i]];
#pragma unroll
  for (int i = 0; i < 4; ++i) if (ok[i]) v[i] = vi[e[i]];
  int rc[4], rv[4];
#pragma unroll
  for (int i = 0; i < 4; ++i) if (ok[i]) rc[i] = atomicAdd(&cntC[c[i]], 1);
#pragma unroll
  for (int i = 0; i < 4; ++i) if (ok[i]) rv[i] = atomicAdd(&cntV[v[i]], 1);
#pragma unroll
  for (int i = 0; i < 4; ++i) if (ok[i]) rankC[e[i]] = rc[i];
#pragma unroll
  for (int i = 0; i < 4; ++i) if (ok[i]) rankV[e[i]] = rv[i];
}

__global__ __launch_bounds__(256) void scan1(const int* __restrict__ cnt,
                                             int* __restrict__ off,
                                             int* __restrict__ bsum, int M) {
  __shared__ int s[256];
  int base = blockIdx.x * 1024 + threadIdx.x * 4;
  int v[4];
  int tot = 0;
#pragma unroll
  for (int i = 0; i < 4; ++i) {
    int idx = base + i;
    v[i] = (idx < M) ? cnt[idx] : 0;
    tot += v[i];
  }
  s[threadIdx.x] = tot;
  __syncthreads();
  for (int d = 1; d < 256; d <<= 1) {
    int t = (threadIdx.x >= d) ? s[threadIdx.x - d] : 0;
    __syncthreads();
    s[threadIdx.x] += t;
    __syncthreads();
  }
  int excl = s[threadIdx.x] - tot;
#pragma unroll
  for (int i = 0; i < 4; ++i) {
    int idx = base + i;
    if (idx < M) off[idx] = excl;
    excl += v[i];
  }
  if (threadIdx.x == 255) bsum[blockIdx.x] = s[255];
}

__global__ __launch_bounds__(256) void scan2(int* __restrict__ bsum, int nb) {
  __shared__ int s[256];
  __shared__ int carry;
  if (threadIdx.x == 0) carry = 0;
  __syncthreads();
  for (int base = 0; base < nb; base += 256) {
    int idx = base + threadIdx.x;
    int v = (idx < nb) ? bsum[idx] : 0;
    s[threadIdx.x] = v;
    __syncthreads();
    for (int d = 1; d < 256; d <<= 1) {
      int t = (threadIdx.x >= d) ? s[threadIdx.x - d] : 0;
      __syncthreads();
      s[threadIdx.x] += t;
      __syncthreads();
    }
    if (idx < nb) bsum[idx] = s[threadIdx.x] - v + carry;
    __syncthreads();
    if (threadIdx.x == 0) carry += s[255];
    __syncthreads();
  }
}

__global__ __launch_bounds__(256) void scan3(int* __restrict__ off,
                                             const int* __restrict__ bsum, int M, int E) {
  int idx = blockIdx.x * 256 + threadIdx.x;
  if (idx < M) off[idx] += bsum[idx >> 10];
  if (idx == M) off[M] = E;
}

// ------- scatter (no atomics): pos = off[dest] + rank; 4 edges/thread -------
__global__ __launch_bounds__(256) void scatter2_kernel(const int* __restrict__ ci,
                                                       const int* __restrict__ vi,
                                                       const float* __restrict__ ew,
                                                       const int* __restrict__ offC,
                                                       const int* __restrict__ offV,
                                                       const int* __restrict__ rankC,
                                                       const int* __restrict__ rankV,
                                                       int2* __restrict__ edataC,
                                                       int2* __restrict__ edataV, int E) {
  int tid = blockIdx.x * 256 + threadIdx.x;
  int T = gridDim.x * 256;
  int e[4], c[4], v[4], wb[4], rc[4], rv[4];
  bool ok[4];
#pragma unroll
  for (int i = 0; i < 4; ++i) {
    e[i] = tid + i * T;
    ok[i] = e[i] < E;
  }
#pragma unroll
  for (int i = 0; i < 4; ++i) if (ok[i]) c[i] = ci[e[i]];
#pragma unroll
  for (int i = 0; i < 4; ++i) if (ok[i]) v[i] = vi[e[i]];
#pragma unroll
  for (int i = 0; i < 4; ++i) if (ok[i]) wb[i] = __float_as_int(ew[e[i]]);
#pragma unroll
  for (int i = 0; i < 4; ++i) if (ok[i]) rc[i] = rankC[e[i]];
#pragma unroll
  for (int i = 0; i < 4; ++i) if (ok[i]) rv[i] = rankV[e[i]];
  int pc[4], pv[4];
#pragma unroll
  for (int i = 0; i < 4; ++i) if (ok[i]) pc[i] = offC[c[i]] + rc[i];
#pragma unroll
  for (int i = 0; i < 4; ++i) if (ok[i]) pv[i] = offV[v[i]] + rv[i];
#pragma unroll
  for (int i = 0; i < 4; ++i) if (ok[i]) edataC[pc[i]] = make_int2(v[i], wb[i]);
#pragma unroll
  for (int i = 0; i < 4; ++i) if (ok[i]) edataV[pv[i]] = make_int2(c[i], wb[i]);
}

// ---------------- segmented gather*gate reduce -> mean (bf16 src/out) ----------------
__global__ __launch_bounds__(256) void seg_reduce(const int* __restrict__ off,
                                                  const int2* __restrict__ edata,
                                                  const float* __restrict__ gw,
                                                  const float* __restrict__ gb,
                                                  const unsigned short* __restrict__ src,
                                                  int srcStride,
                                                  unsigned short* __restrict__ out,
                                                  int outStride, int M) {
  int seg = blockIdx.x * 4 + (threadIdx.x >> 6);
  if (seg >= M) return;
  int j = threadIdx.x & 63;
  int start = off[seg], end = off[seg + 1];
  float gwa = gw[2 * j], gwb = gw[2 * j + 1];
  float gba = gb[2 * j], gbb = gb[2 * j + 1];
  float a0 = 0.f, a1 = 0.f;
  int p = start;
  for (; p + 4 <= end; p += 4) {
    int2 e0 = edata[p], e1 = edata[p + 1], e2 = edata[p + 2], e3 = edata[p + 3];
    unsigned int v0 = *reinterpret_cast<const unsigned int*>(&src[(size_t)e0.x * srcStride + 2 * j]);
    unsigned int v1 = *reinterpret_cast<const unsigned int*>(&src[(size_t)e1.x * srcStride + 2 * j]);
    unsigned int v2 = *reinterpret_cast<const unsigned int*>(&src[(size_t)e2.x * srcStride + 2 * j]);
    unsigned int v3 = *reinterpret_cast<const unsigned int*>(&src[(size_t)e3.x * srcStride + 2 * j]);
    float w0 = __int_as_float(e0.y), w1 = __int_as_float(e1.y);
    float w2 = __int_as_float(e2.y), w3 = __int_as_float(e3.y);
    a0 += bf2f((unsigned short)(v0 & 0xffff)) * sigm(w0 * gwa + gba)
        + bf2f((unsigned short)(v1 & 0xffff)) * sigm(w1 * gwa + gba)
        + bf2f((unsigned short)(v2 & 0xffff)) * sigm(w2 * gwa + gba)
        + bf2f((unsigned short)(v3 & 0xffff)) * sigm(w3 * gwa + gba);
    a1 += bf2f((unsigned short)(v0 >> 16)) * sigm(w0 * gwb + gbb)
        + bf2f((unsigned short)(v1 >> 16)) * sigm(w1 * gwb + gbb)
        + bf2f((unsigned short)(v2 >> 16)) * sigm(w2 * gwb + gbb)
        + bf2f((unsigned short)(v3 >> 16)) * sigm(w3 * gwb + gbb);
  }
  if (p + 2 <= end) {
    int2 e0 = edata[p], e1 = edata[p + 1];
    unsigned int v0 = *reinterpret_cast<const unsigned int*>(&src[(size_t)e0.x * srcStride + 2 * j]);
    unsigned int v1 = *reinterpret_cast<const unsigned int*>(&src[(size_t)e1.x * srcStride + 2 * j]);
    float w0 = __int_as_float(e0.y), w1 = __int_as_float(e1.y);
    a0 += bf2f((unsigned short)(v0 & 0xffff)) * sigm(w0 * gwa + gba)
        + bf2f((unsigned short)(v1 & 0xffff)) * sigm(w1 * gwa + gba);
    a1 += bf2f((unsigned short)(v0 >> 16)) * sigm(w0 * gwb + gbb)
        + bf2f((unsigned short)(v1 >> 16)) * sigm(w1 * gwb + gbb);
    p += 2;
  }
  if (p < end) {
    int2 e0 = edata[p];
    unsigned int v0 = *reinterpret_cast<const unsigned int*>(&src[(size_t)e0.x * srcStride + 2 * j]);
    float w0 = __int_as_float(e0.y);
    a0 += bf2f((unsigned short)(v0 & 0xffff)) * sigm(w0 * gwa + gba);
    a1 += bf2f((unsigned short)(v0 >> 16)) * sigm(w0 * gwb + gbb);
  }
  int cnt = end - start;
  float inv = 1.f / (float)(cnt > 1 ? cnt : 1);
  unsigned int packed = (unsigned int)f2bf(a0 * inv) | ((unsigned int)f2bf(a1 * inv) << 16);
  *reinterpret_cast<unsigned int*>(&out[(size_t)seg * outStride + 2 * j]) = packed;
}

// ------- barrier-free lin GEMM: wave owns 16 rows; W in LDS once; A in registers -------
// out(M x 128) bf16 = bf16(X f32[M][128]) @ Wbf[128][128]^T + bias
template <int OS, bool WBF>
__global__ __launch_bounds__(256) void gemm_lin_reg(const float* __restrict__ X,
                                                    const unsigned short* __restrict__ Wbf,
                                                    const float* __restrict__ bias,
                                                    unsigned short* __restrict__ out,
                                                    unsigned short* __restrict__ bfdst,
                                                    int M) {
  __shared__ unsigned short Bs[128][136];   // [col][k], 272B row stride (2-way free)
  const int tid = threadIdx.x;
  const int lane = tid & 63, wv = tid >> 6;
  const int lr = lane & 15, lg = lane >> 4;
  const int row0 = blockIdx.x * 64 + wv * 16;

  const int arow = row0 + lr;
  const bool rowok = arow < M;
  const float* xrow = X + (size_t)arow * 128;

  // issue all 8 independent X loads upfront (hides HBM latency under W staging)
  float4 x0[4], x1[4];
#pragma unroll
  for (int ks = 0; ks < 4; ++ks) {
    int kb = ks * 32 + lg * 8;
    if (rowok) {
      x0[ks] = *reinterpret_cast<const float4*>(xrow + kb);
      x1[ks] = *reinterpret_cast<const float4*>(xrow + kb + 4);
    } else {
      x0[ks] = make_float4(0.f, 0.f, 0.f, 0.f);
      x1[ks] = x0[ks];
    }
  }

  // stage W once: 16384 u16 / 256 threads = 8 chunks of bf16x8
#pragma unroll
  for (int it = 0; it < 8; ++it) {
    int q = tid + it * 256;
    int n = q >> 4, kq = (q & 15) * 8;
    *reinterpret_cast<bf16x8*>(&Bs[n][kq]) =
        *reinterpret_cast<const bf16x8*>(&Wbf[(size_t)n * 128 + kq]);
  }

  // convert A to bf16 in-reg; optionally persist bf16(X) to bfdst[:,128:256]
  bf16x8 a[4];
#pragma unroll
  for (int ks = 0; ks < 4; ++ks) {
    a[ks] = (bf16x8){(short)f2bf(x0[ks].x), (short)f2bf(x0[ks].y),
                     (short)f2bf(x0[ks].z), (short)f2bf(x0[ks].w),
                     (short)f2bf(x1[ks].x), (short)f2bf(x1[ks].y),
                     (short)f2bf(x1[ks].z), (short)f2bf(x1[ks].w)};
    if (WBF && rowok)
      *reinterpret_cast<bf16x8*>(&bfdst[(size_t)arow * 256 + 128 + ks * 32 + lg * 8]) = a[ks];
  }
  __syncthreads();   // the only barrier: W staged

  f32x4 acc[8];
#pragma unroll
  for (int nf = 0; nf < 8; ++nf) acc[nf] = (f32x4)(0.f);
#pragma unroll
  for (int ks = 0; ks < 4; ++ks) {
#pragma unroll
    for (int nf = 0; nf < 8; ++nf) {
      bf16x8 b = *reinterpret_cast<const bf16x8*>(&Bs[nf * 16 + lr][ks * 32 + lg * 8]);
      acc[nf] = __builtin_amdgcn_mfma_f32_16x16x32_bf16(a[ks], b, acc[nf], 0, 0, 0);
    }
  }

#pragma unroll
  for (int nf = 0; nf < 8; ++nf) {
    int col = nf * 16 + lr;
    float bv = bias[col];
#pragma unroll
    for (int reg = 0; reg < 4; ++reg) {
      int grow = row0 + lg * 4 + reg;
      if (grow < M) out[(size_t)grow * OS + col] = f2bf(acc[nf][reg] + bv);
    }
  }
}

// ------- barrier-light update GEMM (K=256): wave owns 16 rows; wave-local LN; ReLU -------
// CAT: X = Xcat bf16 [M][256].  !CAT: X = concat(agg bf16 [M][128], base f32 [M][128]).
template <bool CAT>
__global__ __launch_bounds__(512) void gemm_upd_reg(const unsigned short* __restrict__ Xa,
                                                    const float* __restrict__ base,
                                                    const unsigned short* __restrict__ Wbf,
                                                    const float* __restrict__ bias,
                                                    const float* __restrict__ lng,
                                                    const float* __restrict__ lnb,
                                                    float* __restrict__ out, int M) {
  __shared__ unsigned short Bs[128][136];   // one K-half of W at a time
  const int tid = threadIdx.x;
  const int lane = tid & 63, wv = tid >> 6;       // 8 waves
  const int lr = lane & 15, lg = lane >> 4;
  const int row0 = blockIdx.x * 128 + wv * 16;
  const int arow = row0 + lr;
  const bool rowok = arow < M;

  // upfront A loads: all K=256 (16B each, fully independent)
  bf16x8 a[8];
  if constexpr (CAT) {
    const unsigned short* xr = Xa + (size_t)arow * 256;
#pragma unroll
    for (int ks = 0; ks < 8; ++ks)
      a[ks] = rowok ? *reinterpret_cast<const bf16x8*>(xr + ks * 32 + lg * 8) : (bf16x8)(short)0;
  } else {
    const unsigned short* ar = Xa + (size_t)arow * 128;
#pragma unroll
    for (int ks = 0; ks < 4; ++ks)
      a[ks] = rowok ? *reinterpret_cast<const bf16x8*>(ar + ks * 32 + lg * 8) : (bf16x8)(short)0;
    const float* br = base + (size_t)arow * 128;
#pragma unroll
    for (int ks = 4; ks < 8; ++ks) {
      float4 f0 = make_float4(0.f, 0.f, 0.f, 0.f), f1 = f0;
      if (rowok) {
        int kb = (ks - 4) * 32 + lg * 8;
        f0 = *reinterpret_cast<const float4*>(br + kb);
        f1 = *reinterpret_cast<const float4*>(br + kb + 4);
      }
      a[ks] = (bf16x8){(short)f2bf(f0.x), (short)f2bf(f0.y), (short)f2bf(f0.z), (short)f2bf(f0.w),
                       (short)f2bf(f1.x), (short)f2bf(f1.y), (short)f2bf(f1.z), (short)f2bf(f1.w)};
    }
  }

  auto stageW = [&](int kh) {
#pragma unroll
    for (int it = 0; it < 4; ++it) {
      int q = tid + it * 512;           // [0,2048) chunks of 8 u16
      int n = q >> 4, kq = (q & 15) * 8;
      *reinterpret_cast<bf16x8*>(&Bs[n][kq]) =
          *reinterpret_cast<const bf16x8*>(&Wbf[(size_t)n * 256 + kh * 128 + kq]);
    }
  };

  f32x4 acc[8];
#pragma unroll
  for (int nf = 0; nf < 8; ++nf) acc[nf] = (f32x4)(0.f);

  stageW(0);
  __syncthreads();
#pragma unroll
  for (int ks = 0; ks < 4; ++ks) {
#pragma unroll
    for (int nf = 0; nf < 8; ++nf) {
      bf16x8 b = *reinterpret_cast<const bf16x8*>(&Bs[nf * 16 + lr][ks * 32 + lg * 8]);
      acc[nf] = __builtin_amdgcn_mfma_f32_16x16x32_bf16(a[ks], b, acc[nf], 0, 0, 0);
    }
  }
  __syncthreads();
  stageW(1);
  __syncthreads();
#pragma unroll
  for (int ks = 4; ks < 8; ++ks) {
#pragma unroll
    for (int nf = 0; nf < 8; ++nf) {
      bf16x8 b = *reinterpret_cast<const bf16x8*>(&Bs[nf * 16 + lr][(ks - 4) * 32 + lg * 8]);
      acc[nf] = __builtin_amdgcn_mfma_f32_16x16x32_bf16(a[ks], b, acc[nf], 0, 0, 0);
    }
  }

  // wave-local LayerNorm + ReLU: row r owned by 16 lanes (lr=0..15), 8 cols each
  float bv[8], gv[8], lv[8];
#pragma unroll
  for (int nf = 0; nf < 8; ++nf) {
    int col = nf * 16 + lr;
    bv[nf] = bias[col];
    gv[nf] = lng[col];
    lv[nf] = lnb[col];
  }
#pragma unroll
  for (int reg = 0; reg < 4; ++reg) {
    float z[8];
    float s = 0.f, q = 0.f;
#pragma unroll
    for (int nf = 0; nf < 8; ++nf) {
      z[nf] = acc[nf][reg] + bv[nf];
      s += z[nf];
      q += z[nf] * z[nf];
    }
#pragma unroll
    for (int m = 1; m < 16; m <<= 1) {
      s += __shfl_xor(s, m);
      q += __shfl_xor(q, m);
    }
    float mean = s * (1.f / 128.f);
    float var = q * (1.f / 128.f) - mean * mean;
    float rstd = rsqrtf(var + LN_EPS);
    int grow = row0 + lg * 4 + reg;
    if (grow < M) {
#pragma unroll
      for (int nf = 0; nf < 8; ++nf) {
        float y = (z[nf] - mean) * rstd * gv[nf] + lv[nf];
        out[(size_t)grow * 128 + nf * 16 + lr] = fmaxf(y, 0.f);
      }
    }
  }
}

extern "C" void kernel_launch(void* const* d_in, const int* in_sizes, int n_in,
                              void* d_out, int out_size, void* d_ws, size_t ws_size,
                              hipStream_t stream) {
  const float* vh = (const float*)d_in[0];
  const float* ch = (const float*)d_in[1];
  const int* ei = (const int*)d_in[2];   // [ci(E), vi(E)]
  const float* ew = (const float*)d_in[3];
  const float* v2c_lin_w = (const float*)d_in[4];
  const float* v2c_lin_b = (const float*)d_in[5];
  const float* v2c_gate_w = (const float*)d_in[6];
  const float* v2c_gate_b = (const float*)d_in[7];
  const float* v2c_upd_w = (const float*)d_in[8];
  const float* v2c_upd_b = (const float*)d_in[9];
  const float* v2c_ln_g = (const float*)d_in[10];
  const float* v2c_ln_b = (const float*)d_in[11];
  const float* c2v_lin_w = (const float*)d_in[12];
  const float* c2v_lin_b = (const float*)d_in[13];
  const float* c2v_gate_w = (const float*)d_in[14];
  const float* c2v_gate_b = (const float*)d_in[15];
  const float* c2v_upd_w = (const float*)d_in[16];
  const float* c2v_upd_b = (const float*)d_in[17];
  const float* c2v_ln_g = (const float*)d_in[18];
  const float* c2v_ln_b = (const float*)d_in[19];

  const int N = in_sizes[0] / 128;
  const int C = in_sizes[1] / 128;
  const int E = in_sizes[3];
  const int* ci = ei;
  const int* vi = ei + E;

  // ---- workspace layout (u16 units) ----
  unsigned short* Xcat = (unsigned short*)d_ws;         // N*256: [agg_v|tmp_v] 0-127, bf16(vh) 128-255
  unsigned short* aggC = Xcat + (size_t)N * 256;        // C*128: agg_c, later tmp_c
  unsigned short* wbf = aggC + (size_t)C * 128;         // 98304
  unsigned short* wbfLinV = wbf;
  unsigned short* wbfUpdV = wbf + 16384;
  unsigned short* wbfLinC = wbf + 49152;
  unsigned short* wbfUpdC = wbf + 65536;
  int* offC = (int*)(wbf + 98304);                      // C+1
  int* offV = offC + (C + 1);                           // N+1
  size_t ofs = (size_t)((offV + (N + 1)) - (int*)d_ws);
  ofs = (ofs + 1) & ~(size_t)1;                         // 8B align
  int2* edataC = (int2*)((int*)d_ws + ofs);             // E
  int2* edataV = edataC + E;                            // E
  // sort scratch aliased into aggC (dead until seg v2c writes it)
  int* cntC = (int*)aggC;
  int* cntV = cntC + C;
  int* bsumS = cntV + N;
  int* rankC = bsumS + 1024;
  int* rankV = rankC + E;

  float* vhNew = (float*)d_out;
  float* chNew = (float*)d_out + (size_t)N * 128;

  // weights f32->bf16 (one launch)
  cvt4_bf16<<<(98304 + 255) / 256, 256, 0, stream>>>(v2c_lin_w, v2c_upd_w, c2v_lin_w,
                                                     c2v_upd_w, wbfLinV, wbfUpdV, wbfLinC,
                                                     wbfUpdC);

  const int egrid4 = (E + 4 * 256 - 1) / (4 * 256);

  // ---- counting sorts: hist+rank -> scans -> scatter (no atomics in scatter) ----
  hipMemsetAsync(cntC, 0, (size_t)(C + N) * sizeof(int), stream);
  hist2_rank<<<egrid4, 256, 0, stream>>>(ci, vi, cntC, cntV, rankC, rankV, E);
  {
    int nb = (C + 1023) / 1024;
    scan1<<<nb, 256, 0, stream>>>(cntC, offC, bsumS, C);
    scan2<<<1, 256, 0, stream>>>(bsumS, nb);
    scan3<<<(C + 1 + 255) / 256, 256, 0, stream>>>(offC, bsumS, C, E);
  }
  {
    int nb = (N + 1023) / 1024;
    scan1<<<nb, 256, 0, stream>>>(cntV, offV, bsumS, N);
    scan2<<<1, 256, 0, stream>>>(bsumS, nb);
    scan3<<<(N + 1 + 255) / 256, 256, 0, stream>>>(offV, bsumS, N, E);
  }
  scatter2_kernel<<<egrid4, 256, 0, stream>>>(ci, vi, ew, offC, offV, rankC, rankV,
                                              edataC, edataV, E);

  // ---- v2c ----
  // lin: tmp_v -> Xcat[:,0:128]; bf16(vh) -> Xcat[:,128:256]
  gemm_lin_reg<256, true><<<(N + 63) / 64, 256, 0, stream>>>(vh, wbfLinV, v2c_lin_b,
                                                             Xcat, Xcat, N);
  seg_reduce<<<(C + 3) / 4, 256, 0, stream>>>(offC, edataC, v2c_gate_w, v2c_gate_b,
                                              Xcat, 256, aggC, 128, C);
  gemm_upd_reg<false><<<(C + 127) / 128, 512, 0, stream>>>(aggC, ch, wbfUpdV, v2c_upd_b,
                                                           v2c_ln_g, v2c_ln_b, chNew, C);

  // ---- c2v ----
  unsigned short* tmpC = aggC;   // reuse (agg_c dead after upd)
  gemm_lin_reg<128, false><<<(C + 63) / 64, 256, 0, stream>>>(chNew, wbfLinC, c2v_lin_b,
                                                              tmpC, nullptr, C);
  // agg_v written over tmp_v in Xcat[:,0:128] (tmp_v dead after v2c seg_reduce)
  seg_reduce<<<(N + 3) / 4, 256, 0, stream>>>(offV, edataV, c2v_gate_w, c2v_gate_b,
                                              tmpC, 128, Xcat, 256, N);
  gemm_upd_reg<true><<<(N + 127) / 128, 512, 0, stream>>>(Xcat, nullptr, wbfUpdC,
                                                          c2v_upd_b, c2v_ln_g, c2v_ln_b,
                                                          vhNew, N);
}

// Round 9
// 330.656 us; speedup vs baseline: 1.3108x; 1.0187x over previous
//
#include <hip/hip_runtime.h>

#define LN_EPS 1e-5f

typedef float f32x4 __attribute__((ext_vector_type(4)));
typedef short bf16x8 __attribute__((ext_vector_type(8)));
typedef unsigned short u16x4 __attribute__((ext_vector_type(4)));

__device__ __forceinline__ unsigned short f2bf(float f) {
  unsigned int u = __float_as_uint(f);
  u = (u + 0x7fffu + ((u >> 16) & 1u)) >> 16;
  return (unsigned short)u;
}
__device__ __forceinline__ float bf2f(unsigned short h) {
  return __uint_as_float((unsigned int)h << 16);
}
__device__ __forceinline__ float sigm(float x) {
  return 1.f / (1.f + __expf(-x));
}

// ---------------- fused f32 -> bf16 convert for all 4 weight mats ----------------
__global__ __launch_bounds__(256) void cvt4_bf16(const float* __restrict__ a,
                                                 const float* __restrict__ b,
                                                 const float* __restrict__ c,
                                                 const float* __restrict__ d,
                                                 unsigned short* __restrict__ oa,
                                                 unsigned short* __restrict__ ob,
                                                 unsigned short* __restrict__ oc,
                                                 unsigned short* __restrict__ od) {
  int i = blockIdx.x * 256 + threadIdx.x;
  if (i < 16384) oa[i] = f2bf(a[i]);
  else if (i < 49152) ob[i - 16384] = f2bf(b[i - 16384]);
  else if (i < 65536) oc[i - 49152] = f2bf(c[i - 49152]);
  else if (i < 98304) od[i - 65536] = f2bf(d[i - 65536]);
}

// ------- fused histogram + rank: rank = atomicAdd return (order within bucket) -------
__global__ __launch_bounds__(256) void hist2_rank(const int* __restrict__ ci,
                                                  const int* __restrict__ vi,
                                                  int* __restrict__ cntC,
                                                  int* __restrict__ cntV,
                                                  int* __restrict__ rankC,
                                                  int* __restrict__ rankV, int E) {
  int tid = blockIdx.x * 256 + threadIdx.x;
  int T = gridDim.x * 256;
  int e[4], c[4], v[4];
  bool ok[4];
#pragma unroll
  for (int i = 0; i < 4; ++i) {
    e[i] = tid + i * T;
    ok[i] = e[i] < E;
  }
#pragma unroll
  for (int i = 0; i < 4; ++i) if (ok[i]) c[i] = ci[e[i]];
#pragma unroll
  for (int i = 0; i < 4; ++i) if (ok[i]) v[i] = vi[e[i]];
  int rc[4], rv[4];
#pragma unroll
  for (int i = 0; i < 4; ++i) if (ok[i]) rc[i] = atomicAdd(&cntC[c[i]], 1);
#pragma unroll
  for (int i = 0; i < 4; ++i) if (ok[i]) rv[i] = atomicAdd(&cntV[v[i]], 1);
#pragma unroll
  for (int i = 0; i < 4; ++i) if (ok[i]) rankC[e[i]] = rc[i];
#pragma unroll
  for (int i = 0; i < 4; ++i) if (ok[i]) rankV[e[i]] = rv[i];
}

__global__ __launch_bounds__(256) void scan1(const int* __restrict__ cnt,
                                             int* __restrict__ off,
                                             int* __restrict__ bsum, int M) {
  __shared__ int s[256];
  int base = blockIdx.x * 1024 + threadIdx.x * 4;
  int v[4];
  int tot = 0;
#pragma unroll
  for (int i = 0; i < 4; ++i) {
    int idx = base + i;
    v[i] = (idx < M) ? cnt[idx] : 0;
    tot += v[i];
  }
  s[threadIdx.x] = tot;
  __syncthreads();
  for (int d = 1; d < 256; d <<= 1) {
    int t = (threadIdx.x >= d) ? s[threadIdx.x - d] : 0;
    __syncthreads();
    s[threadIdx.x] += t;
    __syncthreads();
  }
  int excl = s[threadIdx.x] - tot;
#pragma unroll
  for (int i = 0; i < 4; ++i) {
    int idx = base + i;
    if (idx < M) off[idx] = excl;
    excl += v[i];
  }
  if (threadIdx.x == 255) bsum[blockIdx.x] = s[255];
}

__global__ __launch_bounds__(256) void scan2(int* __restrict__ bsum, int nb) {
  __shared__ int s[256];
  __shared__ int carry;
  if (threadIdx.x == 0) carry = 0;
  __syncthreads();
  for (int base = 0; base < nb; base += 256) {
    int idx = base + threadIdx.x;
    int v = (idx < nb) ? bsum[idx] : 0;
    s[threadIdx.x] = v;
    __syncthreads();
    for (int d = 1; d < 256; d <<= 1) {
      int t = (threadIdx.x >= d) ? s[threadIdx.x - d] : 0;
      __syncthreads();
      s[threadIdx.x] += t;
      __syncthreads();
    }
    if (idx < nb) bsum[idx] = s[threadIdx.x] - v + carry;
    __syncthreads();
    if (threadIdx.x == 0) carry += s[255];
    __syncthreads();
  }
}

__global__ __launch_bounds__(256) void scan3(int* __restrict__ off,
                                             const int* __restrict__ bsum, int M, int E) {
  int idx = blockIdx.x * 256 + threadIdx.x;
  if (idx < M) off[idx] += bsum[idx >> 10];
  if (idx == M) off[M] = E;
}

// ------- scatter (no atomics): pos = off[dest] + rank; 4 edges/thread -------
__global__ __launch_bounds__(256) void scatter2_kernel(const int* __restrict__ ci,
                                                       const int* __restrict__ vi,
                                                       const float* __restrict__ ew,
                                                       const int* __restrict__ offC,
                                                       const int* __restrict__ offV,
                                                       const int* __restrict__ rankC,
                                                       const int* __restrict__ rankV,
                                                       int2* __restrict__ edataC,
                                                       int2* __restrict__ edataV, int E) {
  int tid = blockIdx.x * 256 + threadIdx.x;
  int T = gridDim.x * 256;
  int e[4], c[4], v[4], wb[4], rc[4], rv[4];
  bool ok[4];
#pragma unroll
  for (int i = 0; i < 4; ++i) {
    e[i] = tid + i * T;
    ok[i] = e[i] < E;
  }
#pragma unroll
  for (int i = 0; i < 4; ++i) if (ok[i]) c[i] = ci[e[i]];
#pragma unroll
  for (int i = 0; i < 4; ++i) if (ok[i]) v[i] = vi[e[i]];
#pragma unroll
  for (int i = 0; i < 4; ++i) if (ok[i]) wb[i] = __float_as_int(ew[e[i]]);
#pragma unroll
  for (int i = 0; i < 4; ++i) if (ok[i]) rc[i] = rankC[e[i]];
#pragma unroll
  for (int i = 0; i < 4; ++i) if (ok[i]) rv[i] = rankV[e[i]];
  int pc[4], pv[4];
#pragma unroll
  for (int i = 0; i < 4; ++i) if (ok[i]) pc[i] = offC[c[i]] + rc[i];
#pragma unroll
  for (int i = 0; i < 4; ++i) if (ok[i]) pv[i] = offV[v[i]] + rv[i];
#pragma unroll
  for (int i = 0; i < 4; ++i) if (ok[i]) edataC[pc[i]] = make_int2(v[i], wb[i]);
#pragma unroll
  for (int i = 0; i < 4; ++i) if (ok[i]) edataV[pv[i]] = make_int2(c[i], wb[i]);
}

// ---------------- segmented gather*gate reduce -> mean (bf16 src/out) ----------------
__global__ __launch_bounds__(256) void seg_reduce(const int* __restrict__ off,
                                                  const int2* __restrict__ edata,
                                                  const float* __restrict__ gw,
                                                  const float* __restrict__ gb,
                                                  const unsigned short* __restrict__ src,
                                                  int srcStride,
                                                  unsigned short* __restrict__ out,
                                                  int outStride, int M) {
  int seg = blockIdx.x * 4 + (threadIdx.x >> 6);
  if (seg >= M) return;
  int j = threadIdx.x & 63;
  int start = off[seg], end = off[seg + 1];
  float gwa = gw[2 * j], gwb = gw[2 * j + 1];
  float gba = gb[2 * j], gbb = gb[2 * j + 1];
  float a0 = 0.f, a1 = 0.f;
  int p = start;
  for (; p + 4 <= end; p += 4) {
    int2 e0 = edata[p], e1 = edata[p + 1], e2 = edata[p + 2], e3 = edata[p + 3];
    unsigned int v0 = *reinterpret_cast<const unsigned int*>(&src[(size_t)e0.x * srcStride + 2 * j]);
    unsigned int v1 = *reinterpret_cast<const unsigned int*>(&src[(size_t)e1.x * srcStride + 2 * j]);
    unsigned int v2 = *reinterpret_cast<const unsigned int*>(&src[(size_t)e2.x * srcStride + 2 * j]);
    unsigned int v3 = *reinterpret_cast<const unsigned int*>(&src[(size_t)e3.x * srcStride + 2 * j]);
    float w0 = __int_as_float(e0.y), w1 = __int_as_float(e1.y);
    float w2 = __int_as_float(e2.y), w3 = __int_as_float(e3.y);
    a0 += bf2f((unsigned short)(v0 & 0xffff)) * sigm(w0 * gwa + gba)
        + bf2f((unsigned short)(v1 & 0xffff)) * sigm(w1 * gwa + gba)
        + bf2f((unsigned short)(v2 & 0xffff)) * sigm(w2 * gwa + gba)
        + bf2f((unsigned short)(v3 & 0xffff)) * sigm(w3 * gwa + gba);
    a1 += bf2f((unsigned short)(v0 >> 16)) * sigm(w0 * gwb + gbb)
        + bf2f((unsigned short)(v1 >> 16)) * sigm(w1 * gwb + gbb)
        + bf2f((unsigned short)(v2 >> 16)) * sigm(w2 * gwb + gbb)
        + bf2f((unsigned short)(v3 >> 16)) * sigm(w3 * gwb + gbb);
  }
  if (p + 2 <= end) {
    int2 e0 = edata[p], e1 = edata[p + 1];
    unsigned int v0 = *reinterpret_cast<const unsigned int*>(&src[(size_t)e0.x * srcStride + 2 * j]);
    unsigned int v1 = *reinterpret_cast<const unsigned int*>(&src[(size_t)e1.x * srcStride + 2 * j]);
    float w0 = __int_as_float(e0.y), w1 = __int_as_float(e1.y);
    a0 += bf2f((unsigned short)(v0 & 0xffff)) * sigm(w0 * gwa + gba)
        + bf2f((unsigned short)(v1 & 0xffff)) * sigm(w1 * gwa + gba);
    a1 += bf2f((unsigned short)(v0 >> 16)) * sigm(w0 * gwb + gbb)
        + bf2f((unsigned short)(v1 >> 16)) * sigm(w1 * gwb + gbb);
    p += 2;
  }
  if (p < end) {
    int2 e0 = edata[p];
    unsigned int v0 = *reinterpret_cast<const unsigned int*>(&src[(size_t)e0.x * srcStride + 2 * j]);
    float w0 = __int_as_float(e0.y);
    a0 += bf2f((unsigned short)(v0 & 0xffff)) * sigm(w0 * gwa + gba);
    a1 += bf2f((unsigned short)(v0 >> 16)) * sigm(w0 * gwb + gbb);
  }
  int cnt = end - start;
  float inv = 1.f / (float)(cnt > 1 ? cnt : 1);
  unsigned int packed = (unsigned int)f2bf(a0 * inv) | ((unsigned int)f2bf(a1 * inv) << 16);
  *reinterpret_cast<unsigned int*>(&out[(size_t)seg * outStride + 2 * j]) = packed;
}

// ------- barrier-free lin GEMM: 8 waves x 16 rows; W in LDS once; A in registers -------
// out(M x 128) bf16 = bf16(X f32[M][128]) @ Wbf[128][128]^T + bias
template <int OS, bool WBF>
__global__ __launch_bounds__(512) void gemm_lin_reg(const float* __restrict__ X,
                                                    const unsigned short* __restrict__ Wbf,
                                                    const float* __restrict__ bias,
                                                    unsigned short* __restrict__ out,
                                                    unsigned short* __restrict__ bfdst,
                                                    int M) {
  __shared__ unsigned short Bs[128][136];   // [col][k], 272B row stride
  const int tid = threadIdx.x;
  const int lane = tid & 63, wv = tid >> 6;   // 8 waves
  const int lr = lane & 15, lg = lane >> 4;
  const int row0 = blockIdx.x * 128 + wv * 16;

  const int arow = row0 + lr;
  const bool rowok = arow < M;
  const float* xrow = X + (size_t)arow * 128;

  // issue all 8 independent X loads upfront (hides HBM latency under W staging)
  float4 x0[4], x1[4];
#pragma unroll
  for (int ks = 0; ks < 4; ++ks) {
    int kb = ks * 32 + lg * 8;
    if (rowok) {
      x0[ks] = *reinterpret_cast<const float4*>(xrow + kb);
      x1[ks] = *reinterpret_cast<const float4*>(xrow + kb + 4);
    } else {
      x0[ks] = make_float4(0.f, 0.f, 0.f, 0.f);
      x1[ks] = x0[ks];
    }
  }

  // stage W once: 2048 bf16x8 chunks / 512 threads = 4 each
#pragma unroll
  for (int it = 0; it < 4; ++it) {
    int q = tid + it * 512;
    int n = q >> 4, kq = (q & 15) * 8;
    *reinterpret_cast<bf16x8*>(&Bs[n][kq]) =
        *reinterpret_cast<const bf16x8*>(&Wbf[(size_t)n * 128 + kq]);
  }

  // convert A to bf16 in-reg; optionally persist bf16(X) to bfdst[:,128:256]
  bf16x8 a[4];
#pragma unroll
  for (int ks = 0; ks < 4; ++ks) {
    a[ks] = (bf16x8){(short)f2bf(x0[ks].x), (short)f2bf(x0[ks].y),
                     (short)f2bf(x0[ks].z), (short)f2bf(x0[ks].w),
                     (short)f2bf(x1[ks].x), (short)f2bf(x1[ks].y),
                     (short)f2bf(x1[ks].z), (short)f2bf(x1[ks].w)};
    if (WBF && rowok)
      *reinterpret_cast<bf16x8*>(&bfdst[(size_t)arow * 256 + 128 + ks * 32 + lg * 8]) = a[ks];
  }
  __syncthreads();   // the only barrier: W staged

  f32x4 acc[8];
#pragma unroll
  for (int nf = 0; nf < 8; ++nf) acc[nf] = (f32x4)(0.f);
#pragma unroll
  for (int ks = 0; ks < 4; ++ks) {
#pragma unroll
    for (int nf = 0; nf < 8; ++nf) {
      bf16x8 b = *reinterpret_cast<const bf16x8*>(&Bs[nf * 16 + lr][ks * 32 + lg * 8]);
      acc[nf] = __builtin_amdgcn_mfma_f32_16x16x32_bf16(a[ks], b, acc[nf], 0, 0, 0);
    }
  }

#pragma unroll
  for (int nf = 0; nf < 8; ++nf) {
    int col = nf * 16 + lr;
    float bv = bias[col];
#pragma unroll
    for (int reg = 0; reg < 4; ++reg) {
      int grow = row0 + lg * 4 + reg;
      if (grow < M) out[(size_t)grow * OS + col] = f2bf(acc[nf][reg] + bv);
    }
  }
}

// ------- barrier-light update GEMM (K=256): wave owns 16 rows; wave-local LN; ReLU -------
// CAT: X = Xcat bf16 [M][256].  !CAT: X = concat(agg bf16 [M][128], base f32 [M][128]).
template <bool CAT>
__global__ __launch_bounds__(512) void gemm_upd_reg(const unsigned short* __restrict__ Xa,
                                                    const float* __restrict__ base,
                                                    const unsigned short* __restrict__ Wbf,
                                                    const float* __restrict__ bias,
                                                    const float* __restrict__ lng,
                                                    const float* __restrict__ lnb,
                                                    float* __restrict__ out, int M) {
  __shared__ unsigned short Bs[128][136];   // one K-half of W at a time
  const int tid = threadIdx.x;
  const int lane = tid & 63, wv = tid >> 6;       // 8 waves
  const int lr = lane & 15, lg = lane >> 4;
  const int row0 = blockIdx.x * 128 + wv * 16;
  const int arow = row0 + lr;
  const bool rowok = arow < M;

  // upfront A loads: all K=256 (16B each, fully independent)
  bf16x8 a[8];
  if constexpr (CAT) {
    const unsigned short* xr = Xa + (size_t)arow * 256;
#pragma unroll
    for (int ks = 0; ks < 8; ++ks)
      a[ks] = rowok ? *reinterpret_cast<const bf16x8*>(xr + ks * 32 + lg * 8) : (bf16x8)(short)0;
  } else {
    const unsigned short* ar = Xa + (size_t)arow * 128;
#pragma unroll
    for (int ks = 0; ks < 4; ++ks)
      a[ks] = rowok ? *reinterpret_cast<const bf16x8*>(ar + ks * 32 + lg * 8) : (bf16x8)(short)0;
    const float* br = base + (size_t)arow * 128;
#pragma unroll
    for (int ks = 4; ks < 8; ++ks) {
      float4 f0 = make_float4(0.f, 0.f, 0.f, 0.f), f1 = f0;
      if (rowok) {
        int kb = (ks - 4) * 32 + lg * 8;
        f0 = *reinterpret_cast<const float4*>(br + kb);
        f1 = *reinterpret_cast<const float4*>(br + kb + 4);
      }
      a[ks] = (bf16x8){(short)f2bf(f0.x), (short)f2bf(f0.y), (short)f2bf(f0.z), (short)f2bf(f0.w),
                       (short)f2bf(f1.x), (short)f2bf(f1.y), (short)f2bf(f1.z), (short)f2bf(f1.w)};
    }
  }

  auto stageW = [&](int kh) {
#pragma unroll
    for (int it = 0; it < 4; ++it) {
      int q = tid + it * 512;           // [0,2048) chunks of 8 u16
      int n = q >> 4, kq = (q & 15) * 8;
      *reinterpret_cast<bf16x8*>(&Bs[n][kq]) =
          *reinterpret_cast<const bf16x8*>(&Wbf[(size_t)n * 256 + kh * 128 + kq]);
    }
  };

  f32x4 acc[8];
#pragma unroll
  for (int nf = 0; nf < 8; ++nf) acc[nf] = (f32x4)(0.f);

  stageW(0);
  __syncthreads();
#pragma unroll
  for (int ks = 0; ks < 4; ++ks) {
#pragma unroll
    for (int nf = 0; nf < 8; ++nf) {
      bf16x8 b = *reinterpret_cast<const bf16x8*>(&Bs[nf * 16 + lr][ks * 32 + lg * 8]);
      acc[nf] = __builtin_amdgcn_mfma_f32_16x16x32_bf16(a[ks], b, acc[nf], 0, 0, 0);
    }
  }
  __syncthreads();
  stageW(1);
  __syncthreads();
#pragma unroll
  for (int ks = 4; ks < 8; ++ks) {
#pragma unroll
    for (int nf = 0; nf < 8; ++nf) {
      bf16x8 b = *reinterpret_cast<const bf16x8*>(&Bs[nf * 16 + lr][(ks - 4) * 32 + lg * 8]);
      acc[nf] = __builtin_amdgcn_mfma_f32_16x16x32_bf16(a[ks], b, acc[nf], 0, 0, 0);
    }
  }

  // wave-local LayerNorm + ReLU
  float bv[8], gv[8], lv[8];
#pragma unroll
  for (int nf = 0; nf < 8; ++nf) {
    int col = nf * 16 + lr;
    bv[nf] = bias[col];
    gv[nf] = lng[col];
    lv[nf] = lnb[col];
  }
#pragma unroll
  for (int reg = 0; reg < 4; ++reg) {
    float z[8];
    float s = 0.f, q = 0.f;
#pragma unroll
    for (int nf = 0; nf < 8; ++nf) {
      z[nf] = acc[nf][reg] + bv[nf];
      s += z[nf];
      q += z[nf] * z[nf];
    }
#pragma unroll
    for (int m = 1; m < 16; m <<= 1) {
      s += __shfl_xor(s, m);
      q += __shfl_xor(q, m);
    }
    float mean = s * (1.f / 128.f);
    float var = q * (1.f / 128.f) - mean * mean;
    float rstd = rsqrtf(var + LN_EPS);
    int grow = row0 + lg * 4 + reg;
    if (grow < M) {
#pragma unroll
      for (int nf = 0; nf < 8; ++nf) {
        float y = (z[nf] - mean) * rstd * gv[nf] + lv[nf];
        out[(size_t)grow * 128 + nf * 16 + lr] = fmaxf(y, 0.f);
      }
    }
  }
}

extern "C" void kernel_launch(void* const* d_in, const int* in_sizes, int n_in,
                              void* d_out, int out_size, void* d_ws, size_t ws_size,
                              hipStream_t stream) {
  const float* vh = (const float*)d_in[0];
  const float* ch = (const float*)d_in[1];
  const int* ei = (const int*)d_in[2];   // [ci(E), vi(E)]
  const float* ew = (const float*)d_in[3];
  const float* v2c_lin_w = (const float*)d_in[4];
  const float* v2c_lin_b = (const float*)d_in[5];
  const float* v2c_gate_w = (const float*)d_in[6];
  const float* v2c_gate_b = (const float*)d_in[7];
  const float* v2c_upd_w = (const float*)d_in[8];
  const float* v2c_upd_b = (const float*)d_in[9];
  const float* v2c_ln_g = (const float*)d_in[10];
  const float* v2c_ln_b = (const float*)d_in[11];
  const float* c2v_lin_w = (const float*)d_in[12];
  const float* c2v_lin_b = (const float*)d_in[13];
  const float* c2v_gate_w = (const float*)d_in[14];
  const float* c2v_gate_b = (const float*)d_in[15];
  const float* c2v_upd_w = (const float*)d_in[16];
  const float* c2v_upd_b = (const float*)d_in[17];
  const float* c2v_ln_g = (const float*)d_in[18];
  const float* c2v_ln_b = (const float*)d_in[19];

  const int N = in_sizes[0] / 128;
  const int C = in_sizes[1] / 128;
  const int E = in_sizes[3];
  const int* ci = ei;
  const int* vi = ei + E;

  // ---- workspace layout (u16 units) ----
  unsigned short* Xcat = (unsigned short*)d_ws;         // N*256: [agg_v|tmp_v] 0-127, bf16(vh) 128-255
  unsigned short* aggC = Xcat + (size_t)N * 256;        // C*128: agg_c, later tmp_c
  unsigned short* wbf = aggC + (size_t)C * 128;         // 98304
  unsigned short* wbfLinV = wbf;
  unsigned short* wbfUpdV = wbf + 16384;
  unsigned short* wbfLinC = wbf + 49152;
  unsigned short* wbfUpdC = wbf + 65536;
  int* offC = (int*)(wbf + 98304);                      // C+1
  int* offV = offC + (C + 1);                           // N+1
  size_t ofs = (size_t)((offV + (N + 1)) - (int*)d_ws);
  ofs = (ofs + 1) & ~(size_t)1;                         // 8B align
  int2* edataC = (int2*)((int*)d_ws + ofs);             // E
  int2* edataV = edataC + E;                            // E
  // sort scratch aliased into aggC (dead until seg v2c writes it)
  int* cntC = (int*)aggC;
  int* cntV = cntC + C;
  int* bsumS = cntV + N;
  int* rankC = bsumS + 1024;
  int* rankV = rankC + E;

  float* vhNew = (float*)d_out;
  float* chNew = (float*)d_out + (size_t)N * 128;

  // weights f32->bf16 (one launch)
  cvt4_bf16<<<(98304 + 255) / 256, 256, 0, stream>>>(v2c_lin_w, v2c_upd_w, c2v_lin_w,
                                                     c2v_upd_w, wbfLinV, wbfUpdV, wbfLinC,
                                                     wbfUpdC);

  const int egrid4 = (E + 4 * 256 - 1) / (4 * 256);

  // ---- counting sorts: hist+rank -> scans -> scatter (no atomics in scatter) ----
  hipMemsetAsync(cntC, 0, (size_t)(C + N) * sizeof(int), stream);
  hist2_rank<<<egrid4, 256, 0, stream>>>(ci, vi, cntC, cntV, rankC, rankV, E);
  {
    int nb = (C + 1023) / 1024;
    scan1<<<nb, 256, 0, stream>>>(cntC, offC, bsumS, C);
    scan2<<<1, 256, 0, stream>>>(bsumS, nb);
    scan3<<<(C + 1 + 255) / 256, 256, 0, stream>>>(offC, bsumS, C, E);
  }
  {
    int nb = (N + 1023) / 1024;
    scan1<<<nb, 256, 0, stream>>>(cntV, offV, bsumS, N);
    scan2<<<1, 256, 0, stream>>>(bsumS, nb);
    scan3<<<(N + 1 + 255) / 256, 256, 0, stream>>>(offV, bsumS, N, E);
  }
  scatter2_kernel<<<egrid4, 256, 0, stream>>>(ci, vi, ew, offC, offV, rankC, rankV,
                                              edataC, edataV, E);

  // ---- v2c ----
  // lin: tmp_v -> Xcat[:,0:128]; bf16(vh) -> Xcat[:,128:256]
  gemm_lin_reg<256, true><<<(N + 127) / 128, 512, 0, stream>>>(vh, wbfLinV, v2c_lin_b,
                                                               Xcat, Xcat, N);
  seg_reduce<<<(C + 3) / 4, 256, 0, stream>>>(offC, edataC, v2c_gate_w, v2c_gate_b,
                                              Xcat, 256, aggC, 128, C);
  gemm_upd_reg<false><<<(C + 127) / 128, 512, 0, stream>>>(aggC, ch, wbfUpdV, v2c_upd_b,
                                                           v2c_ln_g, v2c_ln_b, chNew, C);

  // ---- c2v ----
  unsigned short* tmpC = aggC;   // reuse (agg_c dead after upd)
  gemm_lin_reg<128, false><<<(C + 127) / 128, 512, 0, stream>>>(chNew, wbfLinC, c2v_lin_b,
                                                                tmpC, nullptr, C);
  // agg_v written over tmp_v in Xcat[:,0:128] (tmp_v dead after v2c seg_reduce)
  seg_reduce<<<(N + 3) / 4, 256, 0, stream>>>(offV, edataV, c2v_gate_w, c2v_gate_b,
                                              tmpC, 128, Xcat, 256, N);
  gemm_upd_reg<true><<<(N + 127) / 128, 512, 0, stream>>>(Xcat, nullptr, wbfUpdC,
                                                          c2v_upd_b, c2v_ln_g, c2v_ln_b,
                                                          vhNew, N);
}

// Round 10
// 315.576 us; speedup vs baseline: 1.3735x; 1.0478x over previous
//
#include <hip/hip_runtime.h>

#define LN_EPS 1e-5f

typedef float f32x4 __attribute__((ext_vector_type(4)));
typedef short bf16x8 __attribute__((ext_vector_type(8)));
typedef unsigned short u16x4 __attribute__((ext_vector_type(4)));

__device__ __forceinline__ unsigned short f2bf(float f) {
  unsigned int u = __float_as_uint(f);
  u = (u + 0x7fffu + ((u >> 16) & 1u)) >> 16;
  return (unsigned short)u;
}
__device__ __forceinline__ float bf2f(unsigned short h) {
  return __uint_as_float((unsigned int)h << 16);
}
__device__ __forceinline__ float sigm(float x) {
  return 1.f / (1.f + __expf(-x));
}

// ============ fused: weight cvt (blocks [0,384)) + hist+rank (rest) ============
__global__ __launch_bounds__(256) void cvt_hist(const float* __restrict__ wa,
                                                const float* __restrict__ wb,
                                                const float* __restrict__ wc,
                                                const float* __restrict__ wd,
                                                unsigned short* __restrict__ oa,
                                                unsigned short* __restrict__ ob,
                                                unsigned short* __restrict__ oc,
                                                unsigned short* __restrict__ od,
                                                const int* __restrict__ ci,
                                                const int* __restrict__ vi,
                                                int* __restrict__ cntC,
                                                int* __restrict__ cntV,
                                                int* __restrict__ rankC,
                                                int* __restrict__ rankV, int E, int hgrid) {
  if ((int)blockIdx.x < 384) {
    int i = blockIdx.x * 256 + threadIdx.x;
    if (i < 16384) oa[i] = f2bf(wa[i]);
    else if (i < 49152) ob[i - 16384] = f2bf(wb[i - 16384]);
    else if (i < 65536) oc[i - 49152] = f2bf(wc[i - 49152]);
    else if (i < 98304) od[i - 65536] = f2bf(wd[i - 65536]);
    return;
  }
  int hb = blockIdx.x - 384;
  int tid = hb * 256 + threadIdx.x;
  int T = hgrid * 256;
  int e[4], c[4], v[4];
  bool ok[4];
#pragma unroll
  for (int i = 0; i < 4; ++i) {
    e[i] = tid + i * T;
    ok[i] = e[i] < E;
  }
#pragma unroll
  for (int i = 0; i < 4; ++i) if (ok[i]) c[i] = ci[e[i]];
#pragma unroll
  for (int i = 0; i < 4; ++i) if (ok[i]) v[i] = vi[e[i]];
  int rc[4], rv[4];
#pragma unroll
  for (int i = 0; i < 4; ++i) if (ok[i]) rc[i] = atomicAdd(&cntC[c[i]], 1);
#pragma unroll
  for (int i = 0; i < 4; ++i) if (ok[i]) rv[i] = atomicAdd(&cntV[v[i]], 1);
#pragma unroll
  for (int i = 0; i < 4; ++i) if (ok[i]) rankC[e[i]] = rc[i];
#pragma unroll
  for (int i = 0; i < 4; ++i) if (ok[i]) rankV[e[i]] = rv[i];
}

// ============ fused scans: each launch handles both C and N arrays ============
__device__ __forceinline__ void scan1_body(const int* __restrict__ cnt,
                                           int* __restrict__ off,
                                           int* __restrict__ bsum, int M, int bid,
                                           int* s) {
  int base = bid * 1024 + threadIdx.x * 4;
  int v[4];
  int tot = 0;
#pragma unroll
  for (int i = 0; i < 4; ++i) {
    int idx = base + i;
    v[i] = (idx < M) ? cnt[idx] : 0;
    tot += v[i];
  }
  s[threadIdx.x] = tot;
  __syncthreads();
  for (int d = 1; d < 256; d <<= 1) {
    int t = (threadIdx.x >= d) ? s[threadIdx.x - d] : 0;
    __syncthreads();
    s[threadIdx.x] += t;
    __syncthreads();
  }
  int excl = s[threadIdx.x] - tot;
#pragma unroll
  for (int i = 0; i < 4; ++i) {
    int idx = base + i;
    if (idx < M) off[idx] = excl;
    excl += v[i];
  }
  if (threadIdx.x == 255) bsum[bid] = s[255];
}

__global__ __launch_bounds__(256) void scanA(const int* __restrict__ cntC,
                                             int* __restrict__ offC,
                                             int* __restrict__ bsC, int Mc,
                                             const int* __restrict__ cntV,
                                             int* __restrict__ offV,
                                             int* __restrict__ bsV, int Mv, int nbC) {
  __shared__ int s[256];
  if ((int)blockIdx.x < nbC)
    scan1_body(cntC, offC, bsC, Mc, blockIdx.x, s);
  else
    scan1_body(cntV, offV, bsV, Mv, blockIdx.x - nbC, s);
}

__global__ __launch_bounds__(256) void scanB(int* __restrict__ bsC, int nbC,
                                             int* __restrict__ bsV, int nbV) {
  __shared__ int s[256];
  __shared__ int carry;
  int* bsum = (blockIdx.x == 0) ? bsC : bsV;
  int nb = (blockIdx.x == 0) ? nbC : nbV;
  if (threadIdx.x == 0) carry = 0;
  __syncthreads();
  for (int base = 0; base < nb; base += 256) {
    int idx = base + threadIdx.x;
    int v = (idx < nb) ? bsum[idx] : 0;
    s[threadIdx.x] = v;
    __syncthreads();
    for (int d = 1; d < 256; d <<= 1) {
      int t = (threadIdx.x >= d) ? s[threadIdx.x - d] : 0;
      __syncthreads();
      s[threadIdx.x] += t;
      __syncthreads();
    }
    if (idx < nb) bsum[idx] = s[threadIdx.x] - v + carry;
    __syncthreads();
    if (threadIdx.x == 0) carry += s[255];
    __syncthreads();
  }
}

__global__ __launch_bounds__(256) void scanC(int* __restrict__ offC,
                                             const int* __restrict__ bsC, int Mc,
                                             int* __restrict__ offV,
                                             const int* __restrict__ bsV, int Mv,
                                             int E, int gC) {
  if ((int)blockIdx.x < gC) {
    int idx = blockIdx.x * 256 + threadIdx.x;
    if (idx < Mc) offC[idx] += bsC[idx >> 10];
    if (idx == Mc) offC[Mc] = E;
  } else {
    int idx = (blockIdx.x - gC) * 256 + threadIdx.x;
    if (idx < Mv) offV[idx] += bsV[idx >> 10];
    if (idx == Mv) offV[Mv] = E;
  }
}

// ============ fused: scatter (blocks [0,sgrid)) + lin GEMM v2c (rest) ============
// scatter: pos = off[dest] + rank; 2 edges/thread at 512 threads. No atomics.
// lin: 8 waves x 16 rows; W in LDS once; A in registers; out bf16 + bf16(X) persist.
__global__ __launch_bounds__(512) void lin_scatter(
    // lin args
    const float* __restrict__ X, const unsigned short* __restrict__ Wbf,
    const float* __restrict__ bias, unsigned short* __restrict__ out,
    unsigned short* __restrict__ bfdst, int M,
    // scatter args
    const int* __restrict__ ci, const int* __restrict__ vi,
    const float* __restrict__ ew, const int* __restrict__ offC,
    const int* __restrict__ offV, const int* __restrict__ rankC,
    const int* __restrict__ rankV, int2* __restrict__ edataC,
    int2* __restrict__ edataV, int E, int sgrid) {
  __shared__ unsigned short Bs[128][136];
  const int tid = threadIdx.x;

  if ((int)blockIdx.x < sgrid) {
    int gtid = blockIdx.x * 512 + tid;
    int T = sgrid * 512;
    int e[2], c[2], v[2], wb[2], rc[2], rv[2];
    bool ok[2];
#pragma unroll
    for (int i = 0; i < 2; ++i) {
      e[i] = gtid + i * T;
      ok[i] = e[i] < E;
    }
#pragma unroll
    for (int i = 0; i < 2; ++i) if (ok[i]) c[i] = ci[e[i]];
#pragma unroll
    for (int i = 0; i < 2; ++i) if (ok[i]) v[i] = vi[e[i]];
#pragma unroll
    for (int i = 0; i < 2; ++i) if (ok[i]) wb[i] = __float_as_int(ew[e[i]]);
#pragma unroll
    for (int i = 0; i < 2; ++i) if (ok[i]) rc[i] = rankC[e[i]];
#pragma unroll
    for (int i = 0; i < 2; ++i) if (ok[i]) rv[i] = rankV[e[i]];
#pragma unroll
    for (int i = 0; i < 2; ++i) if (ok[i]) edataC[offC[c[i]] + rc[i]] = make_int2(v[i], wb[i]);
#pragma unroll
    for (int i = 0; i < 2; ++i) if (ok[i]) edataV[offV[v[i]] + rv[i]] = make_int2(c[i], wb[i]);
    return;
  }

  const int bid = blockIdx.x - sgrid;
  const int lane = tid & 63, wv = tid >> 6;
  const int lr = lane & 15, lg = lane >> 4;
  const int row0 = bid * 128 + wv * 16;
  const int arow = row0 + lr;
  const bool rowok = arow < M;
  const float* xrow = X + (size_t)arow * 128;

  float4 x0[4], x1[4];
#pragma unroll
  for (int ks = 0; ks < 4; ++ks) {
    int kb = ks * 32 + lg * 8;
    if (rowok) {
      x0[ks] = *reinterpret_cast<const float4*>(xrow + kb);
      x1[ks] = *reinterpret_cast<const float4*>(xrow + kb + 4);
    } else {
      x0[ks] = make_float4(0.f, 0.f, 0.f, 0.f);
      x1[ks] = x0[ks];
    }
  }

#pragma unroll
  for (int it = 0; it < 4; ++it) {
    int q = tid + it * 512;
    int n = q >> 4, kq = (q & 15) * 8;
    *reinterpret_cast<bf16x8*>(&Bs[n][kq]) =
        *reinterpret_cast<const bf16x8*>(&Wbf[(size_t)n * 128 + kq]);
  }

  bf16x8 a[4];
#pragma unroll
  for (int ks = 0; ks < 4; ++ks) {
    a[ks] = (bf16x8){(short)f2bf(x0[ks].x), (short)f2bf(x0[ks].y),
                     (short)f2bf(x0[ks].z), (short)f2bf(x0[ks].w),
                     (short)f2bf(x1[ks].x), (short)f2bf(x1[ks].y),
                     (short)f2bf(x1[ks].z), (short)f2bf(x1[ks].w)};
    if (rowok)
      *reinterpret_cast<bf16x8*>(&bfdst[(size_t)arow * 256 + 128 + ks * 32 + lg * 8]) = a[ks];
  }
  __syncthreads();

  f32x4 acc[8];
#pragma unroll
  for (int nf = 0; nf < 8; ++nf) acc[nf] = (f32x4)(0.f);
#pragma unroll
  for (int ks = 0; ks < 4; ++ks) {
#pragma unroll
    for (int nf = 0; nf < 8; ++nf) {
      bf16x8 b = *reinterpret_cast<const bf16x8*>(&Bs[nf * 16 + lr][ks * 32 + lg * 8]);
      acc[nf] = __builtin_amdgcn_mfma_f32_16x16x32_bf16(a[ks], b, acc[nf], 0, 0, 0);
    }
  }

#pragma unroll
  for (int nf = 0; nf < 8; ++nf) {
    int col = nf * 16 + lr;
    float bv = bias[col];
#pragma unroll
    for (int reg = 0; reg < 4; ++reg) {
      int grow = row0 + lg * 4 + reg;
      if (grow < M) out[(size_t)grow * 256 + col] = f2bf(acc[nf][reg] + bv);
    }
  }
}

// ---------------- segmented gather*gate reduce -> mean (bf16 src/out) ----------------
__global__ __launch_bounds__(256) void seg_reduce(const int* __restrict__ off,
                                                  const int2* __restrict__ edata,
                                                  const float* __restrict__ gw,
                                                  const float* __restrict__ gb,
                                                  const unsigned short* __restrict__ src,
                                                  int srcStride,
                                                  unsigned short* __restrict__ out,
                                                  int outStride, int M) {
  int seg = blockIdx.x * 4 + (threadIdx.x >> 6);
  if (seg >= M) return;
  int j = threadIdx.x & 63;
  int start = off[seg], end = off[seg + 1];
  float gwa = gw[2 * j], gwb = gw[2 * j + 1];
  float gba = gb[2 * j], gbb = gb[2 * j + 1];
  float a0 = 0.f, a1 = 0.f;
  int p = start;
  for (; p + 4 <= end; p += 4) {
    int2 e0 = edata[p], e1 = edata[p + 1], e2 = edata[p + 2], e3 = edata[p + 3];
    unsigned int v0 = *reinterpret_cast<const unsigned int*>(&src[(size_t)e0.x * srcStride + 2 * j]);
    unsigned int v1 = *reinterpret_cast<const unsigned int*>(&src[(size_t)e1.x * srcStride + 2 * j]);
    unsigned int v2 = *reinterpret_cast<const unsigned int*>(&src[(size_t)e2.x * srcStride + 2 * j]);
    unsigned int v3 = *reinterpret_cast<const unsigned int*>(&src[(size_t)e3.x * srcStride + 2 * j]);
    float w0 = __int_as_float(e0.y), w1 = __int_as_float(e1.y);
    float w2 = __int_as_float(e2.y), w3 = __int_as_float(e3.y);
    a0 += bf2f((unsigned short)(v0 & 0xffff)) * sigm(w0 * gwa + gba)
        + bf2f((unsigned short)(v1 & 0xffff)) * sigm(w1 * gwa + gba)
        + bf2f((unsigned short)(v2 & 0xffff)) * sigm(w2 * gwa + gba)
        + bf2f((unsigned short)(v3 & 0xffff)) * sigm(w3 * gwa + gba);
    a1 += bf2f((unsigned short)(v0 >> 16)) * sigm(w0 * gwb + gbb)
        + bf2f((unsigned short)(v1 >> 16)) * sigm(w1 * gwb + gbb)
        + bf2f((unsigned short)(v2 >> 16)) * sigm(w2 * gwb + gbb)
        + bf2f((unsigned short)(v3 >> 16)) * sigm(w3 * gwb + gbb);
  }
  if (p + 2 <= end) {
    int2 e0 = edata[p], e1 = edata[p + 1];
    unsigned int v0 = *reinterpret_cast<const unsigned int*>(&src[(size_t)e0.x * srcStride + 2 * j]);
    unsigned int v1 = *reinterpret_cast<const unsigned int*>(&src[(size_t)e1.x * srcStride + 2 * j]);
    float w0 = __int_as_float(e0.y), w1 = __int_as_float(e1.y);
    a0 += bf2f((unsigned short)(v0 & 0xffff)) * sigm(w0 * gwa + gba)
        + bf2f((unsigned short)(v1 & 0xffff)) * sigm(w1 * gwa + gba);
    a1 += bf2f((unsigned short)(v0 >> 16)) * sigm(w0 * gwb + gbb)
        + bf2f((unsigned short)(v1 >> 16)) * sigm(w1 * gwb + gbb);
    p += 2;
  }
  if (p < end) {
    int2 e0 = edata[p];
    unsigned int v0 = *reinterpret_cast<const unsigned int*>(&src[(size_t)e0.x * srcStride + 2 * j]);
    float w0 = __int_as_float(e0.y);
    a0 += bf2f((unsigned short)(v0 & 0xffff)) * sigm(w0 * gwa + gba);
    a1 += bf2f((unsigned short)(v0 >> 16)) * sigm(w0 * gwb + gbb);
  }
  int cnt = end - start;
  float inv = 1.f / (float)(cnt > 1 ? cnt : 1);
  unsigned int packed = (unsigned int)f2bf(a0 * inv) | ((unsigned int)f2bf(a1 * inv) << 16);
  *reinterpret_cast<unsigned int*>(&out[(size_t)seg * outStride + 2 * j]) = packed;
}

// ------- barrier-free lin GEMM (c2v): 8 waves x 16 rows -------
__global__ __launch_bounds__(512) void gemm_lin_reg(const float* __restrict__ X,
                                                    const unsigned short* __restrict__ Wbf,
                                                    const float* __restrict__ bias,
                                                    unsigned short* __restrict__ out,
                                                    int M) {
  __shared__ unsigned short Bs[128][136];
  const int tid = threadIdx.x;
  const int lane = tid & 63, wv = tid >> 6;
  const int lr = lane & 15, lg = lane >> 4;
  const int row0 = blockIdx.x * 128 + wv * 16;
  const int arow = row0 + lr;
  const bool rowok = arow < M;
  const float* xrow = X + (size_t)arow * 128;

  float4 x0[4], x1[4];
#pragma unroll
  for (int ks = 0; ks < 4; ++ks) {
    int kb = ks * 32 + lg * 8;
    if (rowok) {
      x0[ks] = *reinterpret_cast<const float4*>(xrow + kb);
      x1[ks] = *reinterpret_cast<const float4*>(xrow + kb + 4);
    } else {
      x0[ks] = make_float4(0.f, 0.f, 0.f, 0.f);
      x1[ks] = x0[ks];
    }
  }
#pragma unroll
  for (int it = 0; it < 4; ++it) {
    int q = tid + it * 512;
    int n = q >> 4, kq = (q & 15) * 8;
    *reinterpret_cast<bf16x8*>(&Bs[n][kq]) =
        *reinterpret_cast<const bf16x8*>(&Wbf[(size_t)n * 128 + kq]);
  }
  bf16x8 a[4];
#pragma unroll
  for (int ks = 0; ks < 4; ++ks)
    a[ks] = (bf16x8){(short)f2bf(x0[ks].x), (short)f2bf(x0[ks].y),
                     (short)f2bf(x0[ks].z), (short)f2bf(x0[ks].w),
                     (short)f2bf(x1[ks].x), (short)f2bf(x1[ks].y),
                     (short)f2bf(x1[ks].z), (short)f2bf(x1[ks].w)};
  __syncthreads();

  f32x4 acc[8];
#pragma unroll
  for (int nf = 0; nf < 8; ++nf) acc[nf] = (f32x4)(0.f);
#pragma unroll
  for (int ks = 0; ks < 4; ++ks) {
#pragma unroll
    for (int nf = 0; nf < 8; ++nf) {
      bf16x8 b = *reinterpret_cast<const bf16x8*>(&Bs[nf * 16 + lr][ks * 32 + lg * 8]);
      acc[nf] = __builtin_amdgcn_mfma_f32_16x16x32_bf16(a[ks], b, acc[nf], 0, 0, 0);
    }
  }
#pragma unroll
  for (int nf = 0; nf < 8; ++nf) {
    int col = nf * 16 + lr;
    float bv = bias[col];
#pragma unroll
    for (int reg = 0; reg < 4; ++reg) {
      int grow = row0 + lg * 4 + reg;
      if (grow < M) out[(size_t)grow * 128 + col] = f2bf(acc[nf][reg] + bv);
    }
  }
}

// ------- update GEMM (K=256): wave owns 16 rows; wave-local LN; ReLU -------
template <bool CAT>
__global__ __launch_bounds__(512) void gemm_upd_reg(const unsigned short* __restrict__ Xa,
                                                    const float* __restrict__ base,
                                                    const unsigned short* __restrict__ Wbf,
                                                    const float* __restrict__ bias,
                                                    const float* __restrict__ lng,
                                                    const float* __restrict__ lnb,
                                                    float* __restrict__ out, int M) {
  __shared__ unsigned short Bs[128][136];
  const int tid = threadIdx.x;
  const int lane = tid & 63, wv = tid >> 6;
  const int lr = lane & 15, lg = lane >> 4;
  const int row0 = blockIdx.x * 128 + wv * 16;
  const int arow = row0 + lr;
  const bool rowok = arow < M;

  bf16x8 a[8];
  if constexpr (CAT) {
    const unsigned short* xr = Xa + (size_t)arow * 256;
#pragma unroll
    for (int ks = 0; ks < 8; ++ks)
      a[ks] = rowok ? *reinterpret_cast<const bf16x8*>(xr + ks * 32 + lg * 8) : (bf16x8)(short)0;
  } else {
    const unsigned short* ar = Xa + (size_t)arow * 128;
#pragma unroll
    for (int ks = 0; ks < 4; ++ks)
      a[ks] = rowok ? *reinterpret_cast<const bf16x8*>(ar + ks * 32 + lg * 8) : (bf16x8)(short)0;
    const float* br = base + (size_t)arow * 128;
#pragma unroll
    for (int ks = 4; ks < 8; ++ks) {
      float4 f0 = make_float4(0.f, 0.f, 0.f, 0.f), f1 = f0;
      if (rowok) {
        int kb = (ks - 4) * 32 + lg * 8;
        f0 = *reinterpret_cast<const float4*>(br + kb);
        f1 = *reinterpret_cast<const float4*>(br + kb + 4);
      }
      a[ks] = (bf16x8){(short)f2bf(f0.x), (short)f2bf(f0.y), (short)f2bf(f0.z), (short)f2bf(f0.w),
                       (short)f2bf(f1.x), (short)f2bf(f1.y), (short)f2bf(f1.z), (short)f2bf(f1.w)};
    }
  }

  auto stageW = [&](int kh) {
#pragma unroll
    for (int it = 0; it < 4; ++it) {
      int q = tid + it * 512;
      int n = q >> 4, kq = (q & 15) * 8;
      *reinterpret_cast<bf16x8*>(&Bs[n][kq]) =
          *reinterpret_cast<const bf16x8*>(&Wbf[(size_t)n * 256 + kh * 128 + kq]);
    }
  };

  f32x4 acc[8];
#pragma unroll
  for (int nf = 0; nf < 8; ++nf) acc[nf] = (f32x4)(0.f);

  stageW(0);
  __syncthreads();
#pragma unroll
  for (int ks = 0; ks < 4; ++ks) {
#pragma unroll
    for (int nf = 0; nf < 8; ++nf) {
      bf16x8 b = *reinterpret_cast<const bf16x8*>(&Bs[nf * 16 + lr][ks * 32 + lg * 8]);
      acc[nf] = __builtin_amdgcn_mfma_f32_16x16x32_bf16(a[ks], b, acc[nf], 0, 0, 0);
    }
  }
  __syncthreads();
  stageW(1);
  __syncthreads();
#pragma unroll
  for (int ks = 4; ks < 8; ++ks) {
#pragma unroll
    for (int nf = 0; nf < 8; ++nf) {
      bf16x8 b = *reinterpret_cast<const bf16x8*>(&Bs[nf * 16 + lr][(ks - 4) * 32 + lg * 8]);
      acc[nf] = __builtin_amdgcn_mfma_f32_16x16x32_bf16(a[ks], b, acc[nf], 0, 0, 0);
    }
  }

  float bv[8], gv[8], lv[8];
#pragma unroll
  for (int nf = 0; nf < 8; ++nf) {
    int col = nf * 16 + lr;
    bv[nf] = bias[col];
    gv[nf] = lng[col];
    lv[nf] = lnb[col];
  }
#pragma unroll
  for (int reg = 0; reg < 4; ++reg) {
    float z[8];
    float s = 0.f, q = 0.f;
#pragma unroll
    for (int nf = 0; nf < 8; ++nf) {
      z[nf] = acc[nf][reg] + bv[nf];
      s += z[nf];
      q += z[nf] * z[nf];
    }
#pragma unroll
    for (int m = 1; m < 16; m <<= 1) {
      s += __shfl_xor(s, m);
      q += __shfl_xor(q, m);
    }
    float mean = s * (1.f / 128.f);
    float var = q * (1.f / 128.f) - mean * mean;
    float rstd = rsqrtf(var + LN_EPS);
    int grow = row0 + lg * 4 + reg;
    if (grow < M) {
#pragma unroll
      for (int nf = 0; nf < 8; ++nf) {
        float y = (z[nf] - mean) * rstd * gv[nf] + lv[nf];
        out[(size_t)grow * 128 + nf * 16 + lr] = fmaxf(y, 0.f);
      }
    }
  }
}

extern "C" void kernel_launch(void* const* d_in, const int* in_sizes, int n_in,
                              void* d_out, int out_size, void* d_ws, size_t ws_size,
                              hipStream_t stream) {
  const float* vh = (const float*)d_in[0];
  const float* ch = (const float*)d_in[1];
  const int* ei = (const int*)d_in[2];   // [ci(E), vi(E)]
  const float* ew = (const float*)d_in[3];
  const float* v2c_lin_w = (const float*)d_in[4];
  const float* v2c_lin_b = (const float*)d_in[5];
  const float* v2c_gate_w = (const float*)d_in[6];
  const float* v2c_gate_b = (const float*)d_in[7];
  const float* v2c_upd_w = (const float*)d_in[8];
  const float* v2c_upd_b = (const float*)d_in[9];
  const float* v2c_ln_g = (const float*)d_in[10];
  const float* v2c_ln_b = (const float*)d_in[11];
  const float* c2v_lin_w = (const float*)d_in[12];
  const float* c2v_lin_b = (const float*)d_in[13];
  const float* c2v_gate_w = (const float*)d_in[14];
  const float* c2v_gate_b = (const float*)d_in[15];
  const float* c2v_upd_w = (const float*)d_in[16];
  const float* c2v_upd_b = (const float*)d_in[17];
  const float* c2v_ln_g = (const float*)d_in[18];
  const float* c2v_ln_b = (const float*)d_in[19];

  const int N = in_sizes[0] / 128;
  const int C = in_sizes[1] / 128;
  const int E = in_sizes[3];
  const int* ci = ei;
  const int* vi = ei + E;

  // ---- workspace layout (u16 units) ----
  unsigned short* Xcat = (unsigned short*)d_ws;         // N*256: [agg_v|tmp_v] 0-127, bf16(vh) 128-255
  unsigned short* aggC = Xcat + (size_t)N * 256;        // C*128: agg_c, later tmp_c
  unsigned short* wbf = aggC + (size_t)C * 128;         // 98304
  unsigned short* wbfLinV = wbf;
  unsigned short* wbfUpdV = wbf + 16384;
  unsigned short* wbfLinC = wbf + 49152;
  unsigned short* wbfUpdC = wbf + 65536;
  int* offC = (int*)(wbf + 98304);                      // C+1
  int* offV = offC + (C + 1);                           // N+1
  size_t ofs = (size_t)((offV + (N + 1)) - (int*)d_ws);
  ofs = (ofs + 1) & ~(size_t)1;                         // 8B align
  int2* edataC = (int2*)((int*)d_ws + ofs);             // E
  int2* edataV = edataC + E;                            // E
  // sort scratch aliased into aggC (dead until seg v2c writes it)
  int* cntC = (int*)aggC;
  int* cntV = cntC + C;
  int* bsumC = cntV + N;     // 512
  int* bsumV = bsumC + 512;  // 512
  int* rankC = bsumV + 512;
  int* rankV = rankC + E;

  float* vhNew = (float*)d_out;
  float* chNew = (float*)d_out + (size_t)N * 128;

  const int hgrid = (E + 4 * 256 - 1) / (4 * 256);
  const int sgrid = (E + 2 * 512 - 1) / (2 * 512);
  const int nbC = (C + 1023) / 1024;
  const int nbN = (N + 1023) / 1024;
  const int gC = (C + 1 + 255) / 256;
  const int gN = (N + 1 + 255) / 256;

  // ---- phase 1: weight cvt || hist+rank ----
  hipMemsetAsync(cntC, 0, (size_t)(C + N) * sizeof(int), stream);
  cvt_hist<<<384 + hgrid, 256, 0, stream>>>(v2c_lin_w, v2c_upd_w, c2v_lin_w, c2v_upd_w,
                                            wbfLinV, wbfUpdV, wbfLinC, wbfUpdC,
                                            ci, vi, cntC, cntV, rankC, rankV, E, hgrid);

  // ---- phase 2: fused scans (both directions per launch) ----
  scanA<<<nbC + nbN, 256, 0, stream>>>(cntC, offC, bsumC, C, cntV, offV, bsumV, N, nbC);
  scanB<<<2, 256, 0, stream>>>(bsumC, nbC, bsumV, nbN);
  scanC<<<gC + gN, 256, 0, stream>>>(offC, bsumC, C, offV, bsumV, N, E, gC);

  // ---- phase 3: scatter || lin v2c (independent; fused one launch) ----
  lin_scatter<<<sgrid + (N + 127) / 128, 512, 0, stream>>>(
      vh, wbfLinV, v2c_lin_b, Xcat, Xcat, N,
      ci, vi, ew, offC, offV, rankC, rankV, edataC, edataV, E, sgrid);

  // ---- v2c ----
  seg_reduce<<<(C + 3) / 4, 256, 0, stream>>>(offC, edataC, v2c_gate_w, v2c_gate_b,
                                              Xcat, 256, aggC, 128, C);
  gemm_upd_reg<false><<<(C + 127) / 128, 512, 0, stream>>>(aggC, ch, wbfUpdV, v2c_upd_b,
                                                           v2c_ln_g, v2c_ln_b, chNew, C);

  // ---- c2v ----
  unsigned short* tmpC = aggC;   // reuse (agg_c dead after upd)
  gemm_lin_reg<<<(C + 127) / 128, 512, 0, stream>>>(chNew, wbfLinC, c2v_lin_b, tmpC, C);
  // agg_v written over tmp_v in Xcat[:,0:128] (tmp_v dead after v2c seg_reduce)
  seg_reduce<<<(N + 3) / 4, 256, 0, stream>>>(offV, edataV, c2v_gate_w, c2v_gate_b,
                                              tmpC, 128, Xcat, 256, N);
  gemm_upd_reg<true><<<(N + 127) / 128, 512, 0, stream>>>(Xcat, nullptr, wbfUpdC,
                                                          c2v_upd_b, c2v_ln_g, c2v_ln_b,
                                                          vhNew, N);
}